// Round 6
// baseline (995.989 us; speedup 1.0000x reference)
//
#include <hip/hip_runtime.h>
#include <hip/hip_bf16.h>
#include <math.h>

// ---------- common types ----------
typedef unsigned short u16;
typedef __attribute__((ext_vector_type(8))) short short8;   // 8 bf16 = 4 VGPRs (MFMA A/B frag)
typedef __attribute__((ext_vector_type(4))) short short4v;  // 4 bf16
typedef __attribute__((ext_vector_type(4))) float f32x4;    // MFMA C/D frag

#define CDIM 1024
#define TDIM 1024
#define NROWS 2048   // B*T
#define HEADS 16
#define HD 64
#define F4 4096

// round-to-nearest-even fp32 -> bf16 bits
__device__ __forceinline__ u16 f2bf(float f) {
    union { float f; unsigned u; } v; v.f = f;
    unsigned r = v.u + 0x7fffu + ((v.u >> 16) & 1u);
    return (u16)(r >> 16);
}
__device__ __forceinline__ float bf2f(u16 h) {
    union { unsigned u; float f; } v; v.u = (unsigned)h << 16; return v.f;
}

// async global->LDS, 16 bytes per lane; lds base must be wave-uniform
__device__ __forceinline__ void gload_lds16(const void* g, void* lds) {
    __builtin_amdgcn_global_load_lds(
        (const __attribute__((address_space(1))) unsigned int*)g,
        (__attribute__((address_space(3))) unsigned int*)lds,
        16, 0, 0);
}

// ---------- XCD-bijective + 2D-grouped tile swizzle ----------
// R0 result: FETCH_SIZE 69.7->16.4MB on FFN2 (keep).
__device__ __forceinline__ void tile_map(int& bx, int& by, int& bz)
{
    const int gx = gridDim.x, gy = gridDim.y;
    const int fid = blockIdx.x + gx * (blockIdx.y + gy * blockIdx.z);
    const int nwg = gx * gy * gridDim.z;
    const int q = nwg >> 3, r = nwg & 7;
    const int xcd = fid & 7, t = fid >> 3;
    const int n = ((xcd < r) ? xcd * (q + 1) : r * (q + 1) + (xcd - r) * q) + t;
    const int nxy = gx * gy;
    bz = n / nxy;
    const int xy = n - bz * nxy;
    const int per_group = gx << 3;
    const int grp = xy / per_group;
    const int in = xy - grp * per_group;
    const int y0 = grp << 3;
    const int rem = gy - y0;
    const int gh = rem < 8 ? rem : 8;
    by = y0 + (in % gh);
    bx = in / gh;
}

// ---------- embedding: x = tok_emb[tok] + pos_emb ----------
__global__ __launch_bounds__(256)
void embed_k(const int* __restrict__ tok, const float* __restrict__ te,
             const float* __restrict__ pe, float* __restrict__ X)
{
    const int row = blockIdx.x;          // b*1024 + t
    const int t = row & (TDIM - 1);
    const int tk = tok[row];
    const int c = threadIdx.x * 4;
    float4 a = *reinterpret_cast<const float4*>(te + (size_t)tk * CDIM + c);
    float4 b = *reinterpret_cast<const float4*>(pe + (size_t)t * CDIM + c);
    a.x += b.x; a.y += b.y; a.z += b.z; a.w += b.w;
    *reinterpret_cast<float4*>(X + (size_t)row * CDIM + c) = a;
}

// ---------- layernorm over C=1024, fp32 stats; out bf16 ----------
template<bool BF16OUT>
__global__ __launch_bounds__(256)
void ln_k(const float* __restrict__ X, const float* __restrict__ g,
          const float* __restrict__ be, void* __restrict__ outp)
{
    __shared__ float red[4], red2[4];
    const int row = blockIdx.x, tid = threadIdx.x;
    const float* xr = X + (size_t)row * CDIM;
    const int c = tid * 4;
    float4 xv = *reinterpret_cast<const float4*>(xr + c);
    float s  = xv.x + xv.y + xv.z + xv.w;
    float s2 = xv.x*xv.x + xv.y*xv.y + xv.z*xv.z + xv.w*xv.w;
    #pragma unroll
    for (int off = 32; off; off >>= 1) {
        s  += __shfl_xor(s, off);
        s2 += __shfl_xor(s2, off);
    }
    if ((tid & 63) == 0) { red[tid >> 6] = s; red2[tid >> 6] = s2; }
    __syncthreads();
    const float ts  = red[0] + red[1] + red[2] + red[3];
    const float ts2 = red2[0] + red2[1] + red2[2] + red2[3];
    const float mu  = ts * (1.0f / CDIM);
    const float var = ts2 * (1.0f / CDIM) - mu * mu;
    const float rs  = rsqrtf(var + 1e-5f);
    float4 gv = *reinterpret_cast<const float4*>(g + c);
    float4 bv = *reinterpret_cast<const float4*>(be + c);
    float o0 = (xv.x - mu) * rs * gv.x + bv.x;
    float o1 = (xv.y - mu) * rs * gv.y + bv.y;
    float o2 = (xv.z - mu) * rs * gv.z + bv.z;
    float o3 = (xv.w - mu) * rs * gv.w + bv.w;
    if (BF16OUT) {
        u16 tmp[4] = { f2bf(o0), f2bf(o1), f2bf(o2), f2bf(o3) };
        u16* o = (u16*)outp + (size_t)row * CDIM + c;
        *reinterpret_cast<uint2*>(o) = *reinterpret_cast<const uint2*>(tmp);
    } else {
        float4 ov = { o0, o1, o2, o3 };
        *reinterpret_cast<float4*>((float*)outp + (size_t)row * CDIM + c) = ov;
    }
}

// ---------- fused split-K reduce + residual update + layernorm ----------
// MODE 0: bf16 out [row][C].  MODE 2: head layout -- split-bf16 A' rows
// [e*128 + b*64 + t/16][3072] = [x_hi | x_lo | x_hi]; skips X write-back.
template<int MODE, int NZ>
__global__ __launch_bounds__(256)
void ln_red_k(float* __restrict__ X, const float* __restrict__ P,
              const float* __restrict__ g, const float* __restrict__ be,
              void* __restrict__ outp)
{
    __shared__ float red[4], red2[4];
    const int row = blockIdx.x, tid = threadIdx.x;
    const int c = tid * 4;
    float4 xv = *reinterpret_cast<const float4*>(X + (size_t)row * CDIM + c);
    #pragma unroll
    for (int z = 0; z < NZ; ++z) {
        float4 pv = *reinterpret_cast<const float4*>(P + ((size_t)z * NROWS + row) * CDIM + c);
        xv.x += pv.x; xv.y += pv.y; xv.z += pv.z; xv.w += pv.w;
    }
    if (MODE != 2)
        *reinterpret_cast<float4*>(X + (size_t)row * CDIM + c) = xv;
    float s  = xv.x + xv.y + xv.z + xv.w;
    float s2 = xv.x*xv.x + xv.y*xv.y + xv.z*xv.z + xv.w*xv.w;
    #pragma unroll
    for (int off = 32; off; off >>= 1) {
        s  += __shfl_xor(s, off);
        s2 += __shfl_xor(s2, off);
    }
    if ((tid & 63) == 0) { red[tid >> 6] = s; red2[tid >> 6] = s2; }
    __syncthreads();
    const float ts  = red[0] + red[1] + red[2] + red[3];
    const float ts2 = red2[0] + red2[1] + red2[2] + red2[3];
    const float mu  = ts * (1.0f / CDIM);
    const float var = ts2 * (1.0f / CDIM) - mu * mu;
    const float rs  = rsqrtf(var + 1e-5f);
    float4 gv = *reinterpret_cast<const float4*>(g + c);
    float4 bv = *reinterpret_cast<const float4*>(be + c);
    float o0 = (xv.x - mu) * rs * gv.x + bv.x;
    float o1 = (xv.y - mu) * rs * gv.y + bv.y;
    float o2 = (xv.z - mu) * rs * gv.z + bv.z;
    float o3 = (xv.w - mu) * rs * gv.w + bv.w;
    if (MODE == 0) {
        u16 tmp[4] = { f2bf(o0), f2bf(o1), f2bf(o2), f2bf(o3) };
        u16* o = (u16*)outp + (size_t)row * CDIM + c;
        *reinterpret_cast<uint2*>(o) = *reinterpret_cast<const uint2*>(tmp);
    } else {
        // split-bf16: x = hi + lo to ~2^-16 relative
        u16 hi[4] = { f2bf(o0), f2bf(o1), f2bf(o2), f2bf(o3) };
        u16 lo[4] = { f2bf(o0 - bf2f(hi[0])), f2bf(o1 - bf2f(hi[1])),
                      f2bf(o2 - bf2f(hi[2])), f2bf(o3 - bf2f(hi[3])) };
        const int b = row >> 10, p = row & 1023;
        const int e = p & 15, slot = p >> 4;
        u16* ar = (u16*)outp + (size_t)(e * 128 + b * 64 + slot) * 3072;
        *reinterpret_cast<uint2*>(ar + c)        = *reinterpret_cast<const uint2*>(hi);
        *reinterpret_cast<uint2*>(ar + 1024 + c) = *reinterpret_cast<const uint2*>(lo);
        *reinterpret_cast<uint2*>(ar + 2048 + c) = *reinterpret_cast<const uint2*>(hi);
    }
}

// ---------- weight convert+transpose: W[K][N] fp32 -> Wt[N][K] bf16 ----------
__global__ __launch_bounds__(256)
void convT_k(const float* __restrict__ W, u16* __restrict__ Wt,
             const int K, const int N)
{
    __shared__ u16 s[64][72];
    const int k0 = blockIdx.y * 64, n0 = blockIdx.x * 64;
    const int tr = threadIdx.x >> 4, tc = (threadIdx.x & 15) * 4;
    #pragma unroll
    for (int i = 0; i < 4; ++i) {
        int r = tr + i * 16;
        float4 w = *reinterpret_cast<const float4*>(W + (size_t)(k0 + r) * N + n0 + tc);
        s[r][tc + 0] = f2bf(w.x); s[r][tc + 1] = f2bf(w.y);
        s[r][tc + 2] = f2bf(w.z); s[r][tc + 3] = f2bf(w.w);
    }
    __syncthreads();
    #pragma unroll
    for (int i = 0; i < 4; ++i) {
        int n = tr + i * 16;
        u16 tmp[4];
        #pragma unroll
        for (int e = 0; e < 4; ++e) tmp[e] = s[tc + e][n];
        *reinterpret_cast<uint2*>(Wt + (size_t)(n0 + n) * K + k0 + tc) =
            *reinterpret_cast<const uint2*>(tmp);
    }
}

// ---------- head weight: fp32 [16][101][1024] -> split-bf16 W' [16][128][3072]
__global__ __launch_bounds__(256)
void conv_head_k(const float* __restrict__ HW, u16* __restrict__ Wt)
{
    const int o = blockIdx.x, e = blockIdx.y;   // grid (128, 16)
    const int c = threadIdx.x * 4;
    u16 hi[4] = {0, 0, 0, 0}, lo[4] = {0, 0, 0, 0};
    if (o < 101) {
        float4 w = *reinterpret_cast<const float4*>(HW + ((size_t)e * 101 + o) * 1024 + c);
        hi[0] = f2bf(w.x); hi[1] = f2bf(w.y); hi[2] = f2bf(w.z); hi[3] = f2bf(w.w);
        lo[0] = f2bf(w.x - bf2f(hi[0])); lo[1] = f2bf(w.y - bf2f(hi[1]));
        lo[2] = f2bf(w.z - bf2f(hi[2])); lo[3] = f2bf(w.w - bf2f(hi[3]));
    }
    u16* wr = Wt + (size_t)(e * 128 + o) * 3072;
    *reinterpret_cast<uint2*>(wr + c)        = *reinterpret_cast<const uint2*>(hi);
    *reinterpret_cast<uint2*>(wr + 1024 + c) = *reinterpret_cast<const uint2*>(hi);
    *reinterpret_cast<uint2*>(wr + 2048 + c) = *reinterpret_cast<const uint2*>(lo);
}

// ---------- bias pack: bbuf = concat(bq, bk, bv) for one layer ----------
__global__ __launch_bounds__(256)
void pack_bias_k(const float* __restrict__ a, const float* __restrict__ b,
                 const float* __restrict__ c, float* __restrict__ o)
{
    const int i = threadIdx.x * 4;
    const float* s = blockIdx.x == 0 ? a : blockIdx.x == 1 ? b : c;
    *reinterpret_cast<float4*>(o + (size_t)blockIdx.x * 1024 + i) =
        *reinterpret_cast<const float4*>(s + i);
}

// ---------- GEMM: C[M][N] = A_bf16[M][K] @ Bt_bf16[N][K]^T ----------
// R6: 64x128 tile (was 128x128) -- grids were 1.5-2 blocks/CU (Occupancy 18%,
// grid-limited); halving the M-tile doubles block count -> 3 blocks/CU and
// halves LDS-A (48KB total). 4 waves 2x2, each 32x64 via acc[2][4].
// EPI 0: out bf16 (+V-transpose if vtout)  EPI 1: gelu->bf16
// EPI 2: streaming fp32 partial to resid[bz]
// EPI 3: head -- by in [0,32): e=by>>1, weight base e*128*K; A rows by*64..
template<int EPI>
__global__ __launch_bounds__(256, 2)
void gemm_bt(const u16* __restrict__ A, const u16* __restrict__ Bt,
             const float* __restrict__ bias, u16* __restrict__ outb,
             float* __restrict__ resid, u16* __restrict__ vtout,
             const int N, const int K, const int KCH)
{
    __shared__ __align__(16) u16 sA[2][2][64 * 32];    // [buf][khalf][row*32+k]
    __shared__ __align__(16) u16 sB[2][2][128 * 32];
    const int tid = threadIdx.x;
    const int lane = tid & 63, wv = tid >> 6;
    int bx, by, bz;
    tile_map(bx, by, bz);
    const int m0 = by * 64, n0 = bx * 128;
    const int kbeg = bz * KCH, kend = kbeg + KCH;
    const int fr = lane & 15, fq = lane >> 4;
    const int wm = wv & 1, wn = wv >> 1;
    const int srow = lane >> 2, schunk = (lane & 3) * 8;  // staging: 4 lanes/row
    const u16* Bt2 = (EPI == 3) ? Bt + (size_t)(by >> 1) * 128 * K : Bt;
    f32x4 acc[2][4] = {};

    auto stage = [&](int k0, int buf) {
        #pragma unroll
        for (int kk = 0; kk < 2; ++kk) {
            // A: 64 rows = 4 regions of 16, one per wave
            gload_lds16(A + (size_t)(m0 + wv * 16 + srow) * K + k0 + kk * 32 + schunk,
                        &sA[buf][kk][wv * 512]);
            // B: 128 rows = 8 regions of 16
            #pragma unroll
            for (int i = 0; i < 2; ++i) {
                const int reg = i * 4 + wv;
                gload_lds16(Bt2 + (size_t)(n0 + reg * 16 + srow) * K + k0 + kk * 32 + schunk,
                            &sB[buf][kk][reg * 512]);
            }
        }
    };

    stage(kbeg, 0);
    int cur = 0;
    for (int k0 = kbeg; k0 < kend; k0 += 64) {
        __syncthreads();                    // buf[cur] staged (drains vmcnt)
        if (k0 + 64 < kend) stage(k0 + 64, cur ^ 1);   // prefetch next, hidden by compute
        #pragma unroll
        for (int kk = 0; kk < 2; ++kk) {
            short8 af[2], bf[4];
            #pragma unroll
            for (int mi = 0; mi < 2; ++mi)
                af[mi] = *reinterpret_cast<const short8*>(
                    &sA[cur][kk][(wm * 32 + mi * 16 + fr) * 32 + fq * 8]);
            #pragma unroll
            for (int nj = 0; nj < 4; ++nj)
                bf[nj] = *reinterpret_cast<const short8*>(
                    &sB[cur][kk][(wn * 64 + nj * 16 + fr) * 32 + fq * 8]);
            #pragma unroll
            for (int mi = 0; mi < 2; ++mi)
                #pragma unroll
                for (int nj = 0; nj < 4; ++nj)
                    acc[mi][nj] = __builtin_amdgcn_mfma_f32_16x16x32_bf16(af[mi], bf[nj], acc[mi][nj], 0, 0, 0);
        }
        cur ^= 1;
    }

    #pragma unroll
    for (int nj = 0; nj < 4; ++nj) {
        const int col = n0 + wn * 64 + nj * 16 + fr;
        const float bias_v = (EPI == 3) ? 0.0f
                             : (EPI == 2 && bz != 0) ? 0.0f : bias[col];
        #pragma unroll
        for (int mi = 0; mi < 2; ++mi) {
            const int rowb = m0 + wm * 32 + mi * 16 + fq * 4;
            if (EPI == 0 && vtout != nullptr && col >= 2048) {
                // V part of qkv -> transposed [b*16+h][d][t] bf16, packed 4 t's
                const int bidx = rowb >> 10, t = rowb & 1023, hd = col - 2048;
                u16 t4[4];
                #pragma unroll
                for (int r = 0; r < 4; ++r) t4[r] = f2bf(acc[mi][nj][r] + bias_v);
                *reinterpret_cast<uint2*>(
                    vtout + ((size_t)(bidx * 16 + (hd >> 6)) * 64 + (hd & 63)) * 1024 + t) =
                    *reinterpret_cast<const uint2*>(t4);
            } else {
                #pragma unroll
                for (int r = 0; r < 4; ++r) {
                    const int row = rowb + r;
                    float cv = acc[mi][nj][r] + bias_v;
                    if (EPI == 0) {
                        outb[(size_t)row * N + col] = f2bf(cv);
                    } else if (EPI == 1) {
                        float gl = 0.5f * cv * (1.0f + erff(cv * 0.70710678118654752f));
                        outb[(size_t)row * N + col] = f2bf(gl);
                    } else if (EPI == 2) {
                        resid[((size_t)bz * NROWS + row) * N + col] = cv;  // streaming partial
                    } else {
                        resid[((size_t)bz * NROWS + row) * 128 + col] = cv;
                    }
                }
            }
        }
    }
}

// ---------- head reduce: out[b*1024 + slot*16 + e][col] = sum_z P[z][pr][col] ----------
__global__ __launch_bounds__(128)
void head_red_k(const float* __restrict__ P, float* __restrict__ out)
{
    const int pr = blockIdx.x;             // e*128 + b*64 + slot
    const int col = threadIdx.x;           // [0,128)
    const int e = pr >> 7, rem = pr & 127, b = rem >> 6, slot = rem & 63;
    float s = 0.0f;
    #pragma unroll
    for (int z = 0; z < 8; ++z)
        s += P[((size_t)z * NROWS + pr) * 128 + col];
    if (col < 101)
        out[((size_t)(b << 10) + (slot << 4) + e) * 101 + col] = s;
}

// ---------- flash attention v2: swapped QK^T, in-register P, split-s ----------
__global__ __launch_bounds__(256, 4)
void attn_k(const u16* __restrict__ QKV, const u16* __restrict__ VT,
            float* __restrict__ po, float* __restrict__ plsum)
{
    __shared__ __align__(16) u16 sK[2][64][72];
    __shared__ __align__(16) u16 sV[2][64][72];   // [d][s]
    const int tid = threadIdx.x, lane = tid & 63, wv = tid >> 6;
    const int fr = lane & 15, fq = lane >> 4;
    int bx, by, bz;
    tile_map(bx, by, bz);
    const int qt = bx, h = by, b = bz >> 1, sc = bz & 1;
    const int q0 = qt * 64;
    const int nt = qt + 1, h1 = (nt + 1) >> 1;          // ceil(nt/2)
    const int stbeg = sc ? h1 : 0, stend = sc ? nt : h1;
    const u16* Qb = QKV + (size_t)b * TDIM * 3072 + h * HD;
    const u16* Vb = VT + ((size_t)(b * HEADS + h) * HD) * TDIM;
    const int r0 = tid >> 3, c0 = (tid & 7) * 8;        // staging: 8 chunks/row

    const u16* qp = Qb + (size_t)(q0 + wv * 16 + fr) * 3072 + fq * 8;
    short8 aQ0 = *reinterpret_cast<const short8*>(qp);
    short8 aQ1 = *reinterpret_cast<const short8*>(qp + 32);

    f32x4 o[4] = {};
    float lsum = 0.0f;
    int cur = 0;

    if (stbeg < stend) {
        #pragma unroll
        for (int i = 0; i < 2; ++i) {
            const int r = r0 + i * 32;
            *reinterpret_cast<uint4*>(&sK[0][r][c0]) =
                *reinterpret_cast<const uint4*>(Qb + 1024 + (size_t)(stbeg * 64 + r) * 3072 + c0);
            *reinterpret_cast<uint4*>(&sV[0][r][c0]) =
                *reinterpret_cast<const uint4*>(Vb + (size_t)r * TDIM + stbeg * 64 + c0);
        }
        __syncthreads();
    }

    for (int st = stbeg; st < stend; ++st) {
        const int s0 = st * 64;
        const bool pf = (st + 1) < stend;
        uint4 pk[2], pv[2];
        if (pf) {
            #pragma unroll
            for (int i = 0; i < 2; ++i) {
                const int r = r0 + i * 32;
                pk[i] = *reinterpret_cast<const uint4*>(Qb + 1024 + (size_t)(s0 + 64 + r) * 3072 + c0);
                pv[i] = *reinterpret_cast<const uint4*>(Vb + (size_t)r * TDIM + s0 + 64 + c0);
            }
        }
        // S^T strips: sacc[j][r] = S[q=q0+wv*16+fr][s = s0 + j*16 + fq*4 + r]
        f32x4 sacc[4] = {};
        #pragma unroll
        for (int j = 0; j < 4; ++j) {
            short8 k0f = *reinterpret_cast<const short8*>(&sK[cur][j * 16 + fr][fq * 8]);
            sacc[j] = __builtin_amdgcn_mfma_f32_16x16x32_bf16(k0f, aQ0, sacc[j], 0, 0, 0);
            short8 k1f = *reinterpret_cast<const short8*>(&sK[cur][j * 16 + fr][32 + fq * 8]);
            sacc[j] = __builtin_amdgcn_mfma_f32_16x16x32_bf16(k1f, aQ1, sacc[j], 0, 0, 0);
        }
        const int qrow = q0 + wv * 16 + fr;
        u16 pb[4][4];
        #pragma unroll
        for (int j = 0; j < 4; ++j)
            #pragma unroll
            for (int r = 0; r < 4; ++r) {
                const int scol = s0 + j * 16 + fq * 4 + r;
                const bool keep = (scol <= qrow) && ((scol & 15) != 15);
                const float p = keep ? __expf(sacc[j][r] * 0.125f) : 0.0f;
                const u16 hb = f2bf(p);
                pb[j][r] = hb;
                lsum += bf2f(hb);
            }
        union { unsigned u[4]; short8 v; } a0, a1;
        a0.u[0] = (unsigned)pb[0][0] | ((unsigned)pb[0][1] << 16);
        a0.u[1] = (unsigned)pb[0][2] | ((unsigned)pb[0][3] << 16);
        a0.u[2] = (unsigned)pb[1][0] | ((unsigned)pb[1][1] << 16);
        a0.u[3] = (unsigned)pb[1][2] | ((unsigned)pb[1][3] << 16);
        a1.u[0] = (unsigned)pb[2][0] | ((unsigned)pb[2][1] << 16);
        a1.u[1] = (unsigned)pb[2][2] | ((unsigned)pb[2][3] << 16);
        a1.u[2] = (unsigned)pb[3][0] | ((unsigned)pb[3][1] << 16);
        a1.u[3] = (unsigned)pb[3][2] | ((unsigned)pb[3][3] << 16);
        #pragma unroll
        for (int j = 0; j < 4; ++j) {
            const u16* vrow = &sV[cur][j * 16 + fr][0];
            short4v v0 = *reinterpret_cast<const short4v*>(vrow + fq * 4);
            short4v v1 = *reinterpret_cast<const short4v*>(vrow + 16 + fq * 4);
            short8 bV0 = __builtin_shufflevector(v0, v1, 0, 1, 2, 3, 4, 5, 6, 7);
            o[j] = __builtin_amdgcn_mfma_f32_16x16x32_bf16(a0.v, bV0, o[j], 0, 0, 0);
            short4v v2 = *reinterpret_cast<const short4v*>(vrow + 32 + fq * 4);
            short4v v3 = *reinterpret_cast<const short4v*>(vrow + 48 + fq * 4);
            short8 bV1 = __builtin_shufflevector(v2, v3, 0, 1, 2, 3, 4, 5, 6, 7);
            o[j] = __builtin_amdgcn_mfma_f32_16x16x32_bf16(a1.v, bV1, o[j], 0, 0, 0);
        }
        if (pf) {
            #pragma unroll
            for (int i = 0; i < 2; ++i) {
                const int r = r0 + i * 32;
                *reinterpret_cast<uint4*>(&sK[cur ^ 1][r][c0]) = pk[i];
                *reinterpret_cast<uint4*>(&sV[cur ^ 1][r][c0]) = pv[i];
            }
            __syncthreads();
            cur ^= 1;
        }
    }

    lsum += __shfl_xor(lsum, 16);
    lsum += __shfl_xor(lsum, 32);

    const int tl = (bz * 16 + h) * 16 + qt;
    float* pt = po + (size_t)tl * 4096;
    #pragma unroll
    for (int j = 0; j < 4; ++j)
        #pragma unroll
        for (int r = 0; r < 4; ++r)
            pt[(wv * 16 + fq * 4 + r) * 64 + j * 16 + fr] = o[j][r];
    if (fq == 0) plsum[(size_t)tl * 64 + wv * 16 + fr] = lsum;
}

// ---------- combine split-s attention partials: y = (o0+o1)/(l0+l1) ----------
__global__ __launch_bounds__(256)
void attn_comb_k(const float* __restrict__ po, const float* __restrict__ plsum,
                 u16* __restrict__ Y)
{
    const int qt = blockIdx.x, h = blockIdx.y, b = blockIdx.z;
    const int t0 = ((b * 2 + 0) * 16 + h) * 16 + qt;
    const int t1 = ((b * 2 + 1) * 16 + h) * 16 + qt;
    const float* p0 = po + (size_t)t0 * 4096;
    const float* p1 = po + (size_t)t1 * 4096;
    const float* l0 = plsum + (size_t)t0 * 64;
    const float* l1 = plsum + (size_t)t1 * 64;
    #pragma unroll
    for (int i = 0; i < 4; ++i) {
        const int f4 = threadIdx.x + i * 256;           // float4 index in [0,1024)
        const int q = f4 >> 4, d4 = (f4 & 15) * 4;
        float4 a = *reinterpret_cast<const float4*>(p0 + f4 * 4);
        float4 c = *reinterpret_cast<const float4*>(p1 + f4 * 4);
        const float rl = 1.0f / (l0[q] + l1[q]);
        u16 t4[4] = { f2bf((a.x + c.x) * rl), f2bf((a.y + c.y) * rl),
                      f2bf((a.z + c.z) * rl), f2bf((a.w + c.w) * rl) };
        *reinterpret_cast<uint2*>(
            Y + ((size_t)(b * TDIM + qt * 64 + q)) * CDIM + h * HD + d4) =
            *reinterpret_cast<const uint2*>(t4);
    }
}

// ---------- launch ----------
extern "C" void kernel_launch(void* const* d_in, const int* in_sizes, int n_in,
                              void* d_out, int out_size, void* d_ws, size_t ws_size,
                              hipStream_t stream)
{
    const int*   tokens = (const int*)  d_in[0];
    const float* tok_emb= (const float*)d_in[1];
    const float* pos_emb= (const float*)d_in[2];
    const float* Wq = (const float*)d_in[3];
    const float* bq = (const float*)d_in[4];
    const float* Wk = (const float*)d_in[5];
    const float* bk = (const float*)d_in[6];
    const float* Wv = (const float*)d_in[7];
    const float* bv = (const float*)d_in[8];
    const float* Wp = (const float*)d_in[9];
    const float* bp = (const float*)d_in[10];
    const float* ln1w = (const float*)d_in[11];
    const float* ln1b = (const float*)d_in[12];
    const float* ln2w = (const float*)d_in[13];
    const float* ln2b = (const float*)d_in[14];
    const float* W1 = (const float*)d_in[15];
    const float* b1 = (const float*)d_in[16];
    const float* W2 = (const float*)d_in[17];
    const float* b2 = (const float*)d_in[18];
    const float* lnfw = (const float*)d_in[19];
    const float* lnfb = (const float*)d_in[20];
    const float* head_w = (const float*)d_in[21];
    float* out = (float*)d_out;

    // workspace (68 MB + 12 KB):
    //  0..8M    x fp32 residual          } head phase: hpart fp32 [8][2048][128]
    //  8..12M   hbuf bf16 == yb bf16 (disjoint in time)
    // 12..24M   qkv bf16 / mid bf16 (12..28M)  } head phase: xg A' bf16 [2048][3072]
    // 24..28M   vT bf16
    // 28..36M   wbuf bf16 (converted weights)
    // 36..68M   pbuf fp32 split-K partials / attn po+plsum } head phase:
    //           whp W' bf16 [16][128][3072] at 36..48M
    // 68M..     bbuf fp32 [3072]
    char* ws = (char*)d_ws;
    float* x    = (float*)(ws);
    float* hpart= (float*)(ws);
    u16*   hbuf = (u16*)  (ws + (8u  << 20));
    u16*   yb   = (u16*)  (ws + (8u  << 20));
    u16*   qkv  = (u16*)  (ws + (12u << 20));
    u16*   xg   = (u16*)  (ws + (12u << 20));
    u16*   vt   = (u16*)  (ws + (24u << 20));
    u16*   mid  = (u16*)  (ws + (12u << 20));
    u16*   wbuf = (u16*)  (ws + (28u << 20));
    float* pbuf = (float*)(ws + (36u << 20));
    u16*   whp  = (u16*)  (ws + (36u << 20));
    float* po   = (float*)(ws + (36u << 20));
    float* plsum= (float*)(ws + (53u << 20));
    float* bbuf = (float*)(ws + (68u << 20));

    embed_k<<<NROWS, 256, 0, stream>>>(tokens, tok_emb, pos_emb, x);

    for (int l = 0; l < 4; ++l) {
        const size_t wo = (size_t)l * CDIM * CDIM;
        convT_k<<<dim3(16, 16), 256, 0, stream>>>(Wq + wo, wbuf + 0u * CDIM * CDIM, CDIM, CDIM);
        convT_k<<<dim3(16, 16), 256, 0, stream>>>(Wk + wo, wbuf + 1u * CDIM * CDIM, CDIM, CDIM);
        convT_k<<<dim3(16, 16), 256, 0, stream>>>(Wv + wo, wbuf + 2u * CDIM * CDIM, CDIM, CDIM);
        pack_bias_k<<<3, 256, 0, stream>>>(bq + l * CDIM, bk + l * CDIM, bv + l * CDIM, bbuf);

        if (l == 0)
            ln_k<true><<<NROWS, 256, 0, stream>>>(x, ln1w, ln1b, hbuf);
        else
            ln_red_k<0, 4><<<NROWS, 256, 0, stream>>>(x, pbuf, ln1w + l * CDIM, ln1b + l * CDIM, hbuf);
        gemm_bt<0><<<dim3(24, 32, 1), 256, 0, stream>>>(hbuf, wbuf, bbuf, qkv, nullptr, vt, 3072, CDIM, CDIM);
        attn_k<<<dim3(16, HEADS, 4), 256, 0, stream>>>(qkv, vt, po, plsum);
        attn_comb_k<<<dim3(16, HEADS, 2), 256, 0, stream>>>(po, plsum, yb);

        convT_k<<<dim3(16, 16), 256, 0, stream>>>(Wp + wo, wbuf, CDIM, CDIM);
        gemm_bt<2><<<dim3(8, 32, 2), 256, 0, stream>>>(yb, wbuf, bp + l * CDIM, nullptr, pbuf, nullptr, CDIM, CDIM, 512);

        ln_red_k<0, 2><<<NROWS, 256, 0, stream>>>(x, pbuf, ln2w + l * CDIM, ln2b + l * CDIM, hbuf);
        convT_k<<<dim3(64, 16), 256, 0, stream>>>(W1 + (size_t)l * CDIM * F4, wbuf, CDIM, F4);
        gemm_bt<1><<<dim3(32, 32, 1), 256, 0, stream>>>(hbuf, wbuf, b1 + l * F4, mid, nullptr, nullptr, F4, CDIM, CDIM);
        convT_k<<<dim3(16, 64), 256, 0, stream>>>(W2 + (size_t)l * F4 * CDIM, wbuf, F4, CDIM);
        gemm_bt<2><<<dim3(8, 32, 4), 256, 0, stream>>>(mid, wbuf, b2 + l * CDIM, nullptr, pbuf, nullptr, CDIM, F4, CDIM);
    }

    // head: final LN -> split-bf16 A' (xg), W' (whp), one K=3072 MFMA gemm, reduce
    ln_red_k<2, 4><<<NROWS, 256, 0, stream>>>(x, pbuf, lnfw, lnfb, xg);
    conv_head_k<<<dim3(128, 16), 256, 0, stream>>>(head_w, whp);
    gemm_bt<3><<<dim3(1, 32, 8), 256, 0, stream>>>(xg, whp, nullptr, nullptr, hpart, nullptr, 128, 3072, 384);
    head_red_k<<<NROWS, 128, 0, stream>>>(hpart, out);
}

// Round 7
// 975.334 us; speedup vs baseline: 1.0212x; 1.0212x over previous
//
#include <hip/hip_runtime.h>
#include <hip/hip_bf16.h>
#include <math.h>

// ---------- common types ----------
typedef unsigned short u16;
typedef __attribute__((ext_vector_type(8))) short short8;   // 8 bf16 = 4 VGPRs (MFMA A/B frag)
typedef __attribute__((ext_vector_type(4))) short short4v;  // 4 bf16
typedef __attribute__((ext_vector_type(4))) float f32x4;    // MFMA C/D frag

#define CDIM 1024
#define TDIM 1024
#define NROWS 2048   // B*T
#define HEADS 16
#define HD 64
#define F4 4096

// round-to-nearest-even fp32 -> bf16 bits
__device__ __forceinline__ u16 f2bf(float f) {
    union { float f; unsigned u; } v; v.f = f;
    unsigned r = v.u + 0x7fffu + ((v.u >> 16) & 1u);
    return (u16)(r >> 16);
}
__device__ __forceinline__ float bf2f(u16 h) {
    union { unsigned u; float f; } v; v.u = (unsigned)h << 16; return v.f;
}

// async global->LDS, 16 bytes per lane; lds base must be wave-uniform
__device__ __forceinline__ void gload_lds16(const void* g, void* lds) {
    __builtin_amdgcn_global_load_lds(
        (const __attribute__((address_space(1))) unsigned int*)g,
        (__attribute__((address_space(3))) unsigned int*)lds,
        16, 0, 0);
}

// ---------- XCD-bijective + 2D-grouped tile swizzle ----------
// R0 result: FETCH_SIZE 69.7->16.4MB on FFN2 (keep).
__device__ __forceinline__ void tile_map(int& bx, int& by, int& bz)
{
    const int gx = gridDim.x, gy = gridDim.y;
    const int fid = blockIdx.x + gx * (blockIdx.y + gy * blockIdx.z);
    const int nwg = gx * gy * gridDim.z;
    const int q = nwg >> 3, r = nwg & 7;
    const int xcd = fid & 7, t = fid >> 3;
    const int n = ((xcd < r) ? xcd * (q + 1) : r * (q + 1) + (xcd - r) * q) + t;
    const int nxy = gx * gy;
    bz = n / nxy;
    const int xy = n - bz * nxy;
    const int per_group = gx << 3;
    const int grp = xy / per_group;
    const int in = xy - grp * per_group;
    const int y0 = grp << 3;
    const int rem = gy - y0;
    const int gh = rem < 8 ? rem : 8;
    by = y0 + (in % gh);
    bx = in / gh;
}

// ---------- embedding: x = tok_emb[tok] + pos_emb ----------
__global__ __launch_bounds__(256)
void embed_k(const int* __restrict__ tok, const float* __restrict__ te,
             const float* __restrict__ pe, float* __restrict__ X)
{
    const int row = blockIdx.x;          // b*1024 + t
    const int t = row & (TDIM - 1);
    const int tk = tok[row];
    const int c = threadIdx.x * 4;
    float4 a = *reinterpret_cast<const float4*>(te + (size_t)tk * CDIM + c);
    float4 b = *reinterpret_cast<const float4*>(pe + (size_t)t * CDIM + c);
    a.x += b.x; a.y += b.y; a.z += b.z; a.w += b.w;
    *reinterpret_cast<float4*>(X + (size_t)row * CDIM + c) = a;
}

// ---------- layernorm over C=1024, fp32 stats; out bf16 ----------
template<bool BF16OUT>
__global__ __launch_bounds__(256)
void ln_k(const float* __restrict__ X, const float* __restrict__ g,
          const float* __restrict__ be, void* __restrict__ outp)
{
    __shared__ float red[4], red2[4];
    const int row = blockIdx.x, tid = threadIdx.x;
    const float* xr = X + (size_t)row * CDIM;
    const int c = tid * 4;
    float4 xv = *reinterpret_cast<const float4*>(xr + c);
    float s  = xv.x + xv.y + xv.z + xv.w;
    float s2 = xv.x*xv.x + xv.y*xv.y + xv.z*xv.z + xv.w*xv.w;
    #pragma unroll
    for (int off = 32; off; off >>= 1) {
        s  += __shfl_xor(s, off);
        s2 += __shfl_xor(s2, off);
    }
    if ((tid & 63) == 0) { red[tid >> 6] = s; red2[tid >> 6] = s2; }
    __syncthreads();
    const float ts  = red[0] + red[1] + red[2] + red[3];
    const float ts2 = red2[0] + red2[1] + red2[2] + red2[3];
    const float mu  = ts * (1.0f / CDIM);
    const float var = ts2 * (1.0f / CDIM) - mu * mu;
    const float rs  = rsqrtf(var + 1e-5f);
    float4 gv = *reinterpret_cast<const float4*>(g + c);
    float4 bv = *reinterpret_cast<const float4*>(be + c);
    float o0 = (xv.x - mu) * rs * gv.x + bv.x;
    float o1 = (xv.y - mu) * rs * gv.y + bv.y;
    float o2 = (xv.z - mu) * rs * gv.z + bv.z;
    float o3 = (xv.w - mu) * rs * gv.w + bv.w;
    if (BF16OUT) {
        u16 tmp[4] = { f2bf(o0), f2bf(o1), f2bf(o2), f2bf(o3) };
        u16* o = (u16*)outp + (size_t)row * CDIM + c;
        *reinterpret_cast<uint2*>(o) = *reinterpret_cast<const uint2*>(tmp);
    } else {
        float4 ov = { o0, o1, o2, o3 };
        *reinterpret_cast<float4*>((float*)outp + (size_t)row * CDIM + c) = ov;
    }
}

// ---------- fused split-K reduce + residual update + layernorm ----------
// MODE 0: bf16 out [row][C].  MODE 2: head layout -- split-bf16 A' rows
// [e*128 + b*64 + t/16][3072] = [x_hi | x_lo | x_hi]; skips X write-back.
template<int MODE, int NZ>
__global__ __launch_bounds__(256)
void ln_red_k(float* __restrict__ X, const float* __restrict__ P,
              const float* __restrict__ g, const float* __restrict__ be,
              void* __restrict__ outp)
{
    __shared__ float red[4], red2[4];
    const int row = blockIdx.x, tid = threadIdx.x;
    const int c = tid * 4;
    float4 xv = *reinterpret_cast<const float4*>(X + (size_t)row * CDIM + c);
    #pragma unroll
    for (int z = 0; z < NZ; ++z) {
        float4 pv = *reinterpret_cast<const float4*>(P + ((size_t)z * NROWS + row) * CDIM + c);
        xv.x += pv.x; xv.y += pv.y; xv.z += pv.z; xv.w += pv.w;
    }
    if (MODE != 2)
        *reinterpret_cast<float4*>(X + (size_t)row * CDIM + c) = xv;
    float s  = xv.x + xv.y + xv.z + xv.w;
    float s2 = xv.x*xv.x + xv.y*xv.y + xv.z*xv.z + xv.w*xv.w;
    #pragma unroll
    for (int off = 32; off; off >>= 1) {
        s  += __shfl_xor(s, off);
        s2 += __shfl_xor(s2, off);
    }
    if ((tid & 63) == 0) { red[tid >> 6] = s; red2[tid >> 6] = s2; }
    __syncthreads();
    const float ts  = red[0] + red[1] + red[2] + red[3];
    const float ts2 = red2[0] + red2[1] + red2[2] + red2[3];
    const float mu  = ts * (1.0f / CDIM);
    const float var = ts2 * (1.0f / CDIM) - mu * mu;
    const float rs  = rsqrtf(var + 1e-5f);
    float4 gv = *reinterpret_cast<const float4*>(g + c);
    float4 bv = *reinterpret_cast<const float4*>(be + c);
    float o0 = (xv.x - mu) * rs * gv.x + bv.x;
    float o1 = (xv.y - mu) * rs * gv.y + bv.y;
    float o2 = (xv.z - mu) * rs * gv.z + bv.z;
    float o3 = (xv.w - mu) * rs * gv.w + bv.w;
    if (MODE == 0) {
        u16 tmp[4] = { f2bf(o0), f2bf(o1), f2bf(o2), f2bf(o3) };
        u16* o = (u16*)outp + (size_t)row * CDIM + c;
        *reinterpret_cast<uint2*>(o) = *reinterpret_cast<const uint2*>(tmp);
    } else {
        // split-bf16: x = hi + lo to ~2^-16 relative
        u16 hi[4] = { f2bf(o0), f2bf(o1), f2bf(o2), f2bf(o3) };
        u16 lo[4] = { f2bf(o0 - bf2f(hi[0])), f2bf(o1 - bf2f(hi[1])),
                      f2bf(o2 - bf2f(hi[2])), f2bf(o3 - bf2f(hi[3])) };
        const int b = row >> 10, p = row & 1023;
        const int e = p & 15, slot = p >> 4;
        u16* ar = (u16*)outp + (size_t)(e * 128 + b * 64 + slot) * 3072;
        *reinterpret_cast<uint2*>(ar + c)        = *reinterpret_cast<const uint2*>(hi);
        *reinterpret_cast<uint2*>(ar + 1024 + c) = *reinterpret_cast<const uint2*>(lo);
        *reinterpret_cast<uint2*>(ar + 2048 + c) = *reinterpret_cast<const uint2*>(hi);
    }
}

// ---------- weight convert+transpose: W[K][N] fp32 -> Wt[N][K] bf16 ----------
__global__ __launch_bounds__(256)
void convT_k(const float* __restrict__ W, u16* __restrict__ Wt,
             const int K, const int N)
{
    __shared__ u16 s[64][72];
    const int k0 = blockIdx.y * 64, n0 = blockIdx.x * 64;
    const int tr = threadIdx.x >> 4, tc = (threadIdx.x & 15) * 4;
    #pragma unroll
    for (int i = 0; i < 4; ++i) {
        int r = tr + i * 16;
        float4 w = *reinterpret_cast<const float4*>(W + (size_t)(k0 + r) * N + n0 + tc);
        s[r][tc + 0] = f2bf(w.x); s[r][tc + 1] = f2bf(w.y);
        s[r][tc + 2] = f2bf(w.z); s[r][tc + 3] = f2bf(w.w);
    }
    __syncthreads();
    #pragma unroll
    for (int i = 0; i < 4; ++i) {
        int n = tr + i * 16;
        u16 tmp[4];
        #pragma unroll
        for (int e = 0; e < 4; ++e) tmp[e] = s[tc + e][n];
        *reinterpret_cast<uint2*>(Wt + (size_t)(n0 + n) * K + k0 + tc) =
            *reinterpret_cast<const uint2*>(tmp);
    }
}

// ---------- 3-in-1 1024x1024 convert+transpose (q,k,v weights, one launch) ----------
__global__ __launch_bounds__(256)
void convT3_k(const float* __restrict__ W0, const float* __restrict__ W1p,
              const float* __restrict__ W2p, u16* __restrict__ Wt)
{
    __shared__ u16 s[64][72];
    const float* W = blockIdx.z == 0 ? W0 : blockIdx.z == 1 ? W1p : W2p;
    u16* dst = Wt + (size_t)blockIdx.z * CDIM * CDIM;
    const int k0 = blockIdx.y * 64, n0 = blockIdx.x * 64;
    const int tr = threadIdx.x >> 4, tc = (threadIdx.x & 15) * 4;
    #pragma unroll
    for (int i = 0; i < 4; ++i) {
        int r = tr + i * 16;
        float4 w = *reinterpret_cast<const float4*>(W + (size_t)(k0 + r) * CDIM + n0 + tc);
        s[r][tc + 0] = f2bf(w.x); s[r][tc + 1] = f2bf(w.y);
        s[r][tc + 2] = f2bf(w.z); s[r][tc + 3] = f2bf(w.w);
    }
    __syncthreads();
    #pragma unroll
    for (int i = 0; i < 4; ++i) {
        int n = tr + i * 16;
        u16 tmp[4];
        #pragma unroll
        for (int e = 0; e < 4; ++e) tmp[e] = s[tc + e][n];
        *reinterpret_cast<uint2*>(dst + (size_t)(n0 + n) * CDIM + k0 + tc) =
            *reinterpret_cast<const uint2*>(tmp);
    }
}

// ---------- head weight: fp32 [16][101][1024] -> split-bf16 W' [16][128][3072]
__global__ __launch_bounds__(256)
void conv_head_k(const float* __restrict__ HW, u16* __restrict__ Wt)
{
    const int o = blockIdx.x, e = blockIdx.y;   // grid (128, 16)
    const int c = threadIdx.x * 4;
    u16 hi[4] = {0, 0, 0, 0}, lo[4] = {0, 0, 0, 0};
    if (o < 101) {
        float4 w = *reinterpret_cast<const float4*>(HW + ((size_t)e * 101 + o) * 1024 + c);
        hi[0] = f2bf(w.x); hi[1] = f2bf(w.y); hi[2] = f2bf(w.z); hi[3] = f2bf(w.w);
        lo[0] = f2bf(w.x - bf2f(hi[0])); lo[1] = f2bf(w.y - bf2f(hi[1]));
        lo[2] = f2bf(w.z - bf2f(hi[2])); lo[3] = f2bf(w.w - bf2f(hi[3]));
    }
    u16* wr = Wt + (size_t)(e * 128 + o) * 3072;
    *reinterpret_cast<uint2*>(wr + c)        = *reinterpret_cast<const uint2*>(hi);
    *reinterpret_cast<uint2*>(wr + 1024 + c) = *reinterpret_cast<const uint2*>(hi);
    *reinterpret_cast<uint2*>(wr + 2048 + c) = *reinterpret_cast<const uint2*>(lo);
}

// ---------- bias pack: bbuf = concat(bq, bk, bv) for one layer ----------
__global__ __launch_bounds__(256)
void pack_bias_k(const float* __restrict__ a, const float* __restrict__ b,
                 const float* __restrict__ c, float* __restrict__ o)
{
    const int i = threadIdx.x * 4;
    const float* s = blockIdx.x == 0 ? a : blockIdx.x == 1 ? b : c;
    *reinterpret_cast<float4*>(o + (size_t)blockIdx.x * 1024 + i) =
        *reinterpret_cast<const float4*>(s + i);
}

// ---------- GEMM: C[M][N] = A_bf16[M][K] @ Bt_bf16[N][K]^T ----------
// R7: reverted to R5 128x128 geometry (R6's 64x128 cut MFMA/barrier in half and
// regressed). 4 waves 2x2, acc[4][4], BK=64 two k-half planes, dbuf LDS 64KB,
// one barrier per K-step.
// EPI 0: out bf16 (+V-transpose if vtout)  EPI 1: gelu->bf16
// EPI 2: streaming fp32 partial to resid[bz]
// EPI 3: head -- by in [0,16): weight base by*128*K, grouped A rows by*128..
template<int EPI>
__global__ __launch_bounds__(256, 2)
void gemm_bt(const u16* __restrict__ A, const u16* __restrict__ Bt,
             const float* __restrict__ bias, u16* __restrict__ outb,
             float* __restrict__ resid, u16* __restrict__ vtout,
             const int N, const int K, const int KCH)
{
    __shared__ __align__(16) u16 sA[2][2][128 * 32];   // [buf][khalf][row*32+k]
    __shared__ __align__(16) u16 sB[2][2][128 * 32];
    const int tid = threadIdx.x;
    const int lane = tid & 63, wv = tid >> 6;
    int bx, by, bz;
    tile_map(bx, by, bz);
    const int m0 = by * 128, n0 = bx * 128;
    const int kbeg = bz * KCH, kend = kbeg + KCH;
    const int fr = lane & 15, fq = lane >> 4;
    const int wm = wv & 1, wn = wv >> 1;
    const int srow = lane >> 2, schunk = (lane & 3) * 8;  // staging: 4 lanes/row
    const u16* Bt2 = (EPI == 3) ? Bt + (size_t)by * 128 * K : Bt;
    f32x4 acc[4][4] = {};

    auto stage = [&](int k0, int buf) {
        #pragma unroll
        for (int kk = 0; kk < 2; ++kk)
            #pragma unroll
            for (int i = 0; i < 2; ++i) {
                const int reg = i * 4 + wv;             // 16-row region, 8 regions
                gload_lds16(A  + (size_t)(m0 + reg * 16 + srow) * K + k0 + kk * 32 + schunk,
                            &sA[buf][kk][reg * 512]);
                gload_lds16(Bt2 + (size_t)(n0 + reg * 16 + srow) * K + k0 + kk * 32 + schunk,
                            &sB[buf][kk][reg * 512]);
            }
    };

    stage(kbeg, 0);
    int cur = 0;
    for (int k0 = kbeg; k0 < kend; k0 += 64) {
        __syncthreads();                    // buf[cur] staged (drains vmcnt)
        if (k0 + 64 < kend) stage(k0 + 64, cur ^ 1);   // prefetch next, hidden by compute
        #pragma unroll
        for (int kk = 0; kk < 2; ++kk) {
            short8 af[4], bf[4];
            #pragma unroll
            for (int mi = 0; mi < 4; ++mi)
                af[mi] = *reinterpret_cast<const short8*>(
                    &sA[cur][kk][(wm * 64 + mi * 16 + fr) * 32 + fq * 8]);
            #pragma unroll
            for (int nj = 0; nj < 4; ++nj)
                bf[nj] = *reinterpret_cast<const short8*>(
                    &sB[cur][kk][(wn * 64 + nj * 16 + fr) * 32 + fq * 8]);
            #pragma unroll
            for (int mi = 0; mi < 4; ++mi)
                #pragma unroll
                for (int nj = 0; nj < 4; ++nj)
                    acc[mi][nj] = __builtin_amdgcn_mfma_f32_16x16x32_bf16(af[mi], bf[nj], acc[mi][nj], 0, 0, 0);
        }
        cur ^= 1;
    }

    #pragma unroll
    for (int nj = 0; nj < 4; ++nj) {
        const int col = n0 + wn * 64 + nj * 16 + fr;
        const float bias_v = (EPI == 3) ? 0.0f
                             : (EPI == 2 && bz != 0) ? 0.0f : bias[col];
        #pragma unroll
        for (int mi = 0; mi < 4; ++mi) {
            const int rowb = m0 + wm * 64 + mi * 16 + fq * 4;
            if (EPI == 0 && vtout != nullptr && col >= 2048) {
                // V part of qkv -> transposed [b*16+h][d][t] bf16, packed 4 t's
                const int bidx = rowb >> 10, t = rowb & 1023, hd = col - 2048;
                u16 t4[4];
                #pragma unroll
                for (int r = 0; r < 4; ++r) t4[r] = f2bf(acc[mi][nj][r] + bias_v);
                *reinterpret_cast<uint2*>(
                    vtout + ((size_t)(bidx * 16 + (hd >> 6)) * 64 + (hd & 63)) * 1024 + t) =
                    *reinterpret_cast<const uint2*>(t4);
            } else {
                #pragma unroll
                for (int r = 0; r < 4; ++r) {
                    const int row = rowb + r;
                    float cv = acc[mi][nj][r] + bias_v;
                    if (EPI == 0) {
                        outb[(size_t)row * N + col] = f2bf(cv);
                    } else if (EPI == 1) {
                        float gl = 0.5f * cv * (1.0f + erff(cv * 0.70710678118654752f));
                        outb[(size_t)row * N + col] = f2bf(gl);
                    } else if (EPI == 2) {
                        resid[((size_t)bz * NROWS + row) * N + col] = cv;  // streaming partial
                    } else {
                        resid[((size_t)bz * NROWS + row) * 128 + col] = cv;
                    }
                }
            }
        }
    }
}

// ---------- head reduce: out[b*1024 + slot*16 + e][col] = sum_z P[z][pr][col] ----------
__global__ __launch_bounds__(128)
void head_red_k(const float* __restrict__ P, float* __restrict__ out)
{
    const int pr = blockIdx.x;             // e*128 + b*64 + slot
    const int col = threadIdx.x;           // [0,128)
    const int e = pr >> 7, rem = pr & 127, b = rem >> 6, slot = rem & 63;
    float s = 0.0f;
    #pragma unroll
    for (int z = 0; z < 8; ++z)
        s += P[((size_t)z * NROWS + pr) * 128 + col];
    if (col < 101)
        out[((size_t)(b << 10) + (slot << 4) + e) * 101 + col] = s;
}

// ---------- flash attention v2: swapped QK^T, in-register P, split-s ----------
__global__ __launch_bounds__(256, 4)
void attn_k(const u16* __restrict__ QKV, const u16* __restrict__ VT,
            float* __restrict__ po, float* __restrict__ plsum)
{
    __shared__ __align__(16) u16 sK[2][64][72];
    __shared__ __align__(16) u16 sV[2][64][72];   // [d][s]
    const int tid = threadIdx.x, lane = tid & 63, wv = tid >> 6;
    const int fr = lane & 15, fq = lane >> 4;
    int bx, by, bz;
    tile_map(bx, by, bz);
    const int qt = bx, h = by, b = bz >> 1, sc = bz & 1;
    const int q0 = qt * 64;
    const int nt = qt + 1, h1 = (nt + 1) >> 1;          // ceil(nt/2)
    const int stbeg = sc ? h1 : 0, stend = sc ? nt : h1;
    const u16* Qb = QKV + (size_t)b * TDIM * 3072 + h * HD;
    const u16* Vb = VT + ((size_t)(b * HEADS + h) * HD) * TDIM;
    const int r0 = tid >> 3, c0 = (tid & 7) * 8;        // staging: 8 chunks/row

    const u16* qp = Qb + (size_t)(q0 + wv * 16 + fr) * 3072 + fq * 8;
    short8 aQ0 = *reinterpret_cast<const short8*>(qp);
    short8 aQ1 = *reinterpret_cast<const short8*>(qp + 32);

    f32x4 o[4] = {};
    float lsum = 0.0f;
    int cur = 0;

    if (stbeg < stend) {
        #pragma unroll
        for (int i = 0; i < 2; ++i) {
            const int r = r0 + i * 32;
            *reinterpret_cast<uint4*>(&sK[0][r][c0]) =
                *reinterpret_cast<const uint4*>(Qb + 1024 + (size_t)(stbeg * 64 + r) * 3072 + c0);
            *reinterpret_cast<uint4*>(&sV[0][r][c0]) =
                *reinterpret_cast<const uint4*>(Vb + (size_t)r * TDIM + stbeg * 64 + c0);
        }
        __syncthreads();
    }

    for (int st = stbeg; st < stend; ++st) {
        const int s0 = st * 64;
        const bool pf = (st + 1) < stend;
        uint4 pk[2], pv[2];
        if (pf) {
            #pragma unroll
            for (int i = 0; i < 2; ++i) {
                const int r = r0 + i * 32;
                pk[i] = *reinterpret_cast<const uint4*>(Qb + 1024 + (size_t)(s0 + 64 + r) * 3072 + c0);
                pv[i] = *reinterpret_cast<const uint4*>(Vb + (size_t)r * TDIM + s0 + 64 + c0);
            }
        }
        // S^T strips: sacc[j][r] = S[q=q0+wv*16+fr][s = s0 + j*16 + fq*4 + r]
        f32x4 sacc[4] = {};
        #pragma unroll
        for (int j = 0; j < 4; ++j) {
            short8 k0f = *reinterpret_cast<const short8*>(&sK[cur][j * 16 + fr][fq * 8]);
            sacc[j] = __builtin_amdgcn_mfma_f32_16x16x32_bf16(k0f, aQ0, sacc[j], 0, 0, 0);
            short8 k1f = *reinterpret_cast<const short8*>(&sK[cur][j * 16 + fr][32 + fq * 8]);
            sacc[j] = __builtin_amdgcn_mfma_f32_16x16x32_bf16(k1f, aQ1, sacc[j], 0, 0, 0);
        }
        const int qrow = q0 + wv * 16 + fr;
        u16 pb[4][4];
        #pragma unroll
        for (int j = 0; j < 4; ++j)
            #pragma unroll
            for (int r = 0; r < 4; ++r) {
                const int scol = s0 + j * 16 + fq * 4 + r;
                const bool keep = (scol <= qrow) && ((scol & 15) != 15);
                const float p = keep ? __expf(sacc[j][r] * 0.125f) : 0.0f;
                const u16 hb = f2bf(p);
                pb[j][r] = hb;
                lsum += bf2f(hb);
            }
        union { unsigned u[4]; short8 v; } a0, a1;
        a0.u[0] = (unsigned)pb[0][0] | ((unsigned)pb[0][1] << 16);
        a0.u[1] = (unsigned)pb[0][2] | ((unsigned)pb[0][3] << 16);
        a0.u[2] = (unsigned)pb[1][0] | ((unsigned)pb[1][1] << 16);
        a0.u[3] = (unsigned)pb[1][2] | ((unsigned)pb[1][3] << 16);
        a1.u[0] = (unsigned)pb[2][0] | ((unsigned)pb[2][1] << 16);
        a1.u[1] = (unsigned)pb[2][2] | ((unsigned)pb[2][3] << 16);
        a1.u[2] = (unsigned)pb[3][0] | ((unsigned)pb[3][1] << 16);
        a1.u[3] = (unsigned)pb[3][2] | ((unsigned)pb[3][3] << 16);
        #pragma unroll
        for (int j = 0; j < 4; ++j) {
            const u16* vrow = &sV[cur][j * 16 + fr][0];
            short4v v0 = *reinterpret_cast<const short4v*>(vrow + fq * 4);
            short4v v1 = *reinterpret_cast<const short4v*>(vrow + 16 + fq * 4);
            short8 bV0 = __builtin_shufflevector(v0, v1, 0, 1, 2, 3, 4, 5, 6, 7);
            o[j] = __builtin_amdgcn_mfma_f32_16x16x32_bf16(a0.v, bV0, o[j], 0, 0, 0);
            short4v v2 = *reinterpret_cast<const short4v*>(vrow + 32 + fq * 4);
            short4v v3 = *reinterpret_cast<const short4v*>(vrow + 48 + fq * 4);
            short8 bV1 = __builtin_shufflevector(v2, v3, 0, 1, 2, 3, 4, 5, 6, 7);
            o[j] = __builtin_amdgcn_mfma_f32_16x16x32_bf16(a1.v, bV1, o[j], 0, 0, 0);
        }
        if (pf) {
            #pragma unroll
            for (int i = 0; i < 2; ++i) {
                const int r = r0 + i * 32;
                *reinterpret_cast<uint4*>(&sK[cur ^ 1][r][c0]) = pk[i];
                *reinterpret_cast<uint4*>(&sV[cur ^ 1][r][c0]) = pv[i];
            }
            __syncthreads();
            cur ^= 1;
        }
    }

    lsum += __shfl_xor(lsum, 16);
    lsum += __shfl_xor(lsum, 32);

    const int tl = (bz * 16 + h) * 16 + qt;
    float* pt = po + (size_t)tl * 4096;
    #pragma unroll
    for (int j = 0; j < 4; ++j)
        #pragma unroll
        for (int r = 0; r < 4; ++r)
            pt[(wv * 16 + fq * 4 + r) * 64 + j * 16 + fr] = o[j][r];
    if (fq == 0) plsum[(size_t)tl * 64 + wv * 16 + fr] = lsum;
}

// ---------- combine split-s attention partials: y = (o0+o1)/(l0+l1) ----------
__global__ __launch_bounds__(256)
void attn_comb_k(const float* __restrict__ po, const float* __restrict__ plsum,
                 u16* __restrict__ Y)
{
    const int qt = blockIdx.x, h = blockIdx.y, b = blockIdx.z;
    const int t0 = ((b * 2 + 0) * 16 + h) * 16 + qt;
    const int t1 = ((b * 2 + 1) * 16 + h) * 16 + qt;
    const float* p0 = po + (size_t)t0 * 4096;
    const float* p1 = po + (size_t)t1 * 4096;
    const float* l0 = plsum + (size_t)t0 * 64;
    const float* l1 = plsum + (size_t)t1 * 64;
    #pragma unroll
    for (int i = 0; i < 4; ++i) {
        const int f4 = threadIdx.x + i * 256;           // float4 index in [0,1024)
        const int q = f4 >> 4, d4 = (f4 & 15) * 4;
        float4 a = *reinterpret_cast<const float4*>(p0 + f4 * 4);
        float4 c = *reinterpret_cast<const float4*>(p1 + f4 * 4);
        const float rl = 1.0f / (l0[q] + l1[q]);
        u16 t4[4] = { f2bf((a.x + c.x) * rl), f2bf((a.y + c.y) * rl),
                      f2bf((a.z + c.z) * rl), f2bf((a.w + c.w) * rl) };
        *reinterpret_cast<uint2*>(
            Y + ((size_t)(b * TDIM + qt * 64 + q)) * CDIM + h * HD + d4) =
            *reinterpret_cast<const uint2*>(t4);
    }
}

// ---------- launch ----------
extern "C" void kernel_launch(void* const* d_in, const int* in_sizes, int n_in,
                              void* d_out, int out_size, void* d_ws, size_t ws_size,
                              hipStream_t stream)
{
    const int*   tokens = (const int*)  d_in[0];
    const float* tok_emb= (const float*)d_in[1];
    const float* pos_emb= (const float*)d_in[2];
    const float* Wq = (const float*)d_in[3];
    const float* bq = (const float*)d_in[4];
    const float* Wk = (const float*)d_in[5];
    const float* bk = (const float*)d_in[6];
    const float* Wv = (const float*)d_in[7];
    const float* bv = (const float*)d_in[8];
    const float* Wp = (const float*)d_in[9];
    const float* bp = (const float*)d_in[10];
    const float* ln1w = (const float*)d_in[11];
    const float* ln1b = (const float*)d_in[12];
    const float* ln2w = (const float*)d_in[13];
    const float* ln2b = (const float*)d_in[14];
    const float* W1 = (const float*)d_in[15];
    const float* b1 = (const float*)d_in[16];
    const float* W2 = (const float*)d_in[17];
    const float* b2 = (const float*)d_in[18];
    const float* lnfw = (const float*)d_in[19];
    const float* lnfb = (const float*)d_in[20];
    const float* head_w = (const float*)d_in[21];
    float* out = (float*)d_out;

    // workspace (100 MB + 12 KB; harness ws is >=256MB per fill WRITE_SIZE):
    //  0..8M    x fp32 residual          } head phase: hpart fp32 [8][2048][128]
    //  8..12M   hbuf bf16 == yb bf16 (disjoint in time)
    // 12..24M   qkv bf16 / mid bf16 (12..28M)  } head phase: xg A' bf16 [2048][3072]
    // 24..28M   vT bf16
    // 28..36M   wbuf bf16 (converted weights)
    // 36..100M  pbuf fp32 split-K partials (up to 8 x 8MB) / attn po+plsum /
    //           head-phase whp W' bf16 [16][128][3072] at 36..48M
    // 100M..    bbuf fp32 [3072]
    char* ws = (char*)d_ws;
    float* x    = (float*)(ws);
    float* hpart= (float*)(ws);
    u16*   hbuf = (u16*)  (ws + (8u  << 20));
    u16*   yb   = (u16*)  (ws + (8u  << 20));
    u16*   qkv  = (u16*)  (ws + (12u << 20));
    u16*   xg   = (u16*)  (ws + (12u << 20));
    u16*   vt   = (u16*)  (ws + (24u << 20));
    u16*   mid  = (u16*)  (ws + (12u << 20));
    u16*   wbuf = (u16*)  (ws + (28u << 20));
    float* pbuf = (float*)(ws + (36u << 20));
    u16*   whp  = (u16*)  (ws + (36u << 20));
    float* po   = (float*)(ws + (36u << 20));
    float* plsum= (float*)(ws + (53u << 20));
    float* bbuf = (float*)(ws + (100u << 20));

    embed_k<<<NROWS, 256, 0, stream>>>(tokens, tok_emb, pos_emb, x);

    for (int l = 0; l < 4; ++l) {
        const size_t wo = (size_t)l * CDIM * CDIM;
        convT3_k<<<dim3(16, 16, 3), 256, 0, stream>>>(Wq + wo, Wk + wo, Wv + wo, wbuf);
        pack_bias_k<<<3, 256, 0, stream>>>(bq + l * CDIM, bk + l * CDIM, bv + l * CDIM, bbuf);

        if (l == 0)
            ln_k<true><<<NROWS, 256, 0, stream>>>(x, ln1w, ln1b, hbuf);
        else
            ln_red_k<0, 8><<<NROWS, 256, 0, stream>>>(x, pbuf, ln1w + l * CDIM, ln1b + l * CDIM, hbuf);
        gemm_bt<0><<<dim3(24, 16, 1), 256, 0, stream>>>(hbuf, wbuf, bbuf, qkv, nullptr, vt, 3072, CDIM, CDIM);
        attn_k<<<dim3(16, HEADS, 4), 256, 0, stream>>>(qkv, vt, po, plsum);
        attn_comb_k<<<dim3(16, HEADS, 2), 256, 0, stream>>>(po, plsum, yb);

        convT_k<<<dim3(16, 16), 256, 0, stream>>>(Wp + wo, wbuf, CDIM, CDIM);
        gemm_bt<2><<<dim3(8, 16, 4), 256, 0, stream>>>(yb, wbuf, bp + l * CDIM, nullptr, pbuf, nullptr, CDIM, CDIM, 256);

        ln_red_k<0, 4><<<NROWS, 256, 0, stream>>>(x, pbuf, ln2w + l * CDIM, ln2b + l * CDIM, hbuf);
        convT_k<<<dim3(64, 16), 256, 0, stream>>>(W1 + (size_t)l * CDIM * F4, wbuf, CDIM, F4);
        gemm_bt<1><<<dim3(32, 16, 1), 256, 0, stream>>>(hbuf, wbuf, b1 + l * F4, mid, nullptr, nullptr, F4, CDIM, CDIM);
        convT_k<<<dim3(16, 64), 256, 0, stream>>>(W2 + (size_t)l * F4 * CDIM, wbuf, F4, CDIM);
        gemm_bt<2><<<dim3(8, 16, 8), 256, 0, stream>>>(mid, wbuf, b2 + l * CDIM, nullptr, pbuf, nullptr, CDIM, F4, 512);
    }

    // head: final LN -> split-bf16 A' (xg), W' (whp), one K=3072 MFMA gemm, reduce
    ln_red_k<2, 8><<<NROWS, 256, 0, stream>>>(x, pbuf, lnfw, lnfb, xg);
    conv_head_k<<<dim3(128, 16), 256, 0, stream>>>(head_w, whp);
    gemm_bt<3><<<dim3(1, 16, 8), 256, 0, stream>>>(xg, whp, nullptr, nullptr, hpart, nullptr, 128, 3072, 384);
    head_red_k<<<NROWS, 128, 0, stream>>>(hpart, out);
}

// Round 8
// 932.417 us; speedup vs baseline: 1.0682x; 1.0460x over previous
//
#include <hip/hip_runtime.h>
#include <hip/hip_bf16.h>
#include <math.h>

// ---------- common types ----------
typedef unsigned short u16;
typedef __attribute__((ext_vector_type(8))) short short8;   // 8 bf16 = 4 VGPRs (MFMA A/B frag)
typedef __attribute__((ext_vector_type(4))) short short4v;  // 4 bf16
typedef __attribute__((ext_vector_type(4))) float f32x4;    // MFMA C/D frag

#define CDIM 1024
#define TDIM 1024
#define NROWS 2048   // B*T
#define HEADS 16
#define HD 64
#define F4 4096

// round-to-nearest-even fp32 -> bf16 bits
__device__ __forceinline__ u16 f2bf(float f) {
    union { float f; unsigned u; } v; v.f = f;
    unsigned r = v.u + 0x7fffu + ((v.u >> 16) & 1u);
    return (u16)(r >> 16);
}
__device__ __forceinline__ float bf2f(u16 h) {
    union { unsigned u; float f; } v; v.u = (unsigned)h << 16; return v.f;
}

// async global->LDS, 16 bytes per lane; lds base must be wave-uniform
__device__ __forceinline__ void gload_lds16(const void* g, void* lds) {
    __builtin_amdgcn_global_load_lds(
        (const __attribute__((address_space(1))) unsigned int*)g,
        (__attribute__((address_space(3))) unsigned int*)lds,
        16, 0, 0);
}

// ---------- XCD-bijective + 2D-grouped tile swizzle ----------
// R0 result: FETCH_SIZE 69.7->16.4MB on FFN2 (keep).
__device__ __forceinline__ void tile_map(int& bx, int& by, int& bz)
{
    const int gx = gridDim.x, gy = gridDim.y;
    const int fid = blockIdx.x + gx * (blockIdx.y + gy * blockIdx.z);
    const int nwg = gx * gy * gridDim.z;
    const int q = nwg >> 3, r = nwg & 7;
    const int xcd = fid & 7, t = fid >> 3;
    const int n = ((xcd < r) ? xcd * (q + 1) : r * (q + 1) + (xcd - r) * q) + t;
    const int nxy = gx * gy;
    bz = n / nxy;
    const int xy = n - bz * nxy;
    const int per_group = gx << 3;
    const int grp = xy / per_group;
    const int in = xy - grp * per_group;
    const int y0 = grp << 3;
    const int rem = gy - y0;
    const int gh = rem < 8 ? rem : 8;
    by = y0 + (in % gh);
    bx = in / gh;
}

// ---------- embedding: x = tok_emb[tok] + pos_emb ----------
__global__ __launch_bounds__(256)
void embed_k(const int* __restrict__ tok, const float* __restrict__ te,
             const float* __restrict__ pe, float* __restrict__ X)
{
    const int row = blockIdx.x;          // b*1024 + t
    const int t = row & (TDIM - 1);
    const int tk = tok[row];
    const int c = threadIdx.x * 4;
    float4 a = *reinterpret_cast<const float4*>(te + (size_t)tk * CDIM + c);
    float4 b = *reinterpret_cast<const float4*>(pe + (size_t)t * CDIM + c);
    a.x += b.x; a.y += b.y; a.z += b.z; a.w += b.w;
    *reinterpret_cast<float4*>(X + (size_t)row * CDIM + c) = a;
}

// ---------- layernorm over C=1024, fp32 stats; out bf16 ----------
template<bool BF16OUT>
__global__ __launch_bounds__(256)
void ln_k(const float* __restrict__ X, const float* __restrict__ g,
          const float* __restrict__ be, void* __restrict__ outp)
{
    __shared__ float red[4], red2[4];
    const int row = blockIdx.x, tid = threadIdx.x;
    const float* xr = X + (size_t)row * CDIM;
    const int c = tid * 4;
    float4 xv = *reinterpret_cast<const float4*>(xr + c);
    float s  = xv.x + xv.y + xv.z + xv.w;
    float s2 = xv.x*xv.x + xv.y*xv.y + xv.z*xv.z + xv.w*xv.w;
    #pragma unroll
    for (int off = 32; off; off >>= 1) {
        s  += __shfl_xor(s, off);
        s2 += __shfl_xor(s2, off);
    }
    if ((tid & 63) == 0) { red[tid >> 6] = s; red2[tid >> 6] = s2; }
    __syncthreads();
    const float ts  = red[0] + red[1] + red[2] + red[3];
    const float ts2 = red2[0] + red2[1] + red2[2] + red2[3];
    const float mu  = ts * (1.0f / CDIM);
    const float var = ts2 * (1.0f / CDIM) - mu * mu;
    const float rs  = rsqrtf(var + 1e-5f);
    float4 gv = *reinterpret_cast<const float4*>(g + c);
    float4 bv = *reinterpret_cast<const float4*>(be + c);
    float o0 = (xv.x - mu) * rs * gv.x + bv.x;
    float o1 = (xv.y - mu) * rs * gv.y + bv.y;
    float o2 = (xv.z - mu) * rs * gv.z + bv.z;
    float o3 = (xv.w - mu) * rs * gv.w + bv.w;
    if (BF16OUT) {
        u16 tmp[4] = { f2bf(o0), f2bf(o1), f2bf(o2), f2bf(o3) };
        u16* o = (u16*)outp + (size_t)row * CDIM + c;
        *reinterpret_cast<uint2*>(o) = *reinterpret_cast<const uint2*>(tmp);
    } else {
        float4 ov = { o0, o1, o2, o3 };
        *reinterpret_cast<float4*>((float*)outp + (size_t)row * CDIM + c) = ov;
    }
}

// ---------- fused split-K reduce + residual update + layernorm ----------
// MODE 0: bf16 out [row][C].  MODE 2: head layout -- split-bf16 A' rows
// [e*128 + b*64 + t/16][3072] = [x_hi | x_lo | x_hi]; skips X write-back.
template<int MODE, int NZ>
__global__ __launch_bounds__(256)
void ln_red_k(float* __restrict__ X, const float* __restrict__ P,
              const float* __restrict__ g, const float* __restrict__ be,
              void* __restrict__ outp)
{
    __shared__ float red[4], red2[4];
    const int row = blockIdx.x, tid = threadIdx.x;
    const int c = tid * 4;
    float4 xv = *reinterpret_cast<const float4*>(X + (size_t)row * CDIM + c);
    #pragma unroll
    for (int z = 0; z < NZ; ++z) {
        float4 pv = *reinterpret_cast<const float4*>(P + ((size_t)z * NROWS + row) * CDIM + c);
        xv.x += pv.x; xv.y += pv.y; xv.z += pv.z; xv.w += pv.w;
    }
    if (MODE != 2)
        *reinterpret_cast<float4*>(X + (size_t)row * CDIM + c) = xv;
    float s  = xv.x + xv.y + xv.z + xv.w;
    float s2 = xv.x*xv.x + xv.y*xv.y + xv.z*xv.z + xv.w*xv.w;
    #pragma unroll
    for (int off = 32; off; off >>= 1) {
        s  += __shfl_xor(s, off);
        s2 += __shfl_xor(s2, off);
    }
    if ((tid & 63) == 0) { red[tid >> 6] = s; red2[tid >> 6] = s2; }
    __syncthreads();
    const float ts  = red[0] + red[1] + red[2] + red[3];
    const float ts2 = red2[0] + red2[1] + red2[2] + red2[3];
    const float mu  = ts * (1.0f / CDIM);
    const float var = ts2 * (1.0f / CDIM) - mu * mu;
    const float rs  = rsqrtf(var + 1e-5f);
    float4 gv = *reinterpret_cast<const float4*>(g + c);
    float4 bv = *reinterpret_cast<const float4*>(be + c);
    float o0 = (xv.x - mu) * rs * gv.x + bv.x;
    float o1 = (xv.y - mu) * rs * gv.y + bv.y;
    float o2 = (xv.z - mu) * rs * gv.z + bv.z;
    float o3 = (xv.w - mu) * rs * gv.w + bv.w;
    if (MODE == 0) {
        u16 tmp[4] = { f2bf(o0), f2bf(o1), f2bf(o2), f2bf(o3) };
        u16* o = (u16*)outp + (size_t)row * CDIM + c;
        *reinterpret_cast<uint2*>(o) = *reinterpret_cast<const uint2*>(tmp);
    } else {
        // split-bf16: x = hi + lo to ~2^-16 relative
        u16 hi[4] = { f2bf(o0), f2bf(o1), f2bf(o2), f2bf(o3) };
        u16 lo[4] = { f2bf(o0 - bf2f(hi[0])), f2bf(o1 - bf2f(hi[1])),
                      f2bf(o2 - bf2f(hi[2])), f2bf(o3 - bf2f(hi[3])) };
        const int b = row >> 10, p = row & 1023;
        const int e = p & 15, slot = p >> 4;
        u16* ar = (u16*)outp + (size_t)(e * 128 + b * 64 + slot) * 3072;
        *reinterpret_cast<uint2*>(ar + c)        = *reinterpret_cast<const uint2*>(hi);
        *reinterpret_cast<uint2*>(ar + 1024 + c) = *reinterpret_cast<const uint2*>(lo);
        *reinterpret_cast<uint2*>(ar + 2048 + c) = *reinterpret_cast<const uint2*>(hi);
    }
}

// ---------- weight convert+transpose: W[K][N] fp32 -> Wt[N][K] bf16 ----------
__global__ __launch_bounds__(256)
void convT_k(const float* __restrict__ W, u16* __restrict__ Wt,
             const int K, const int N)
{
    __shared__ u16 s[64][72];
    const int k0 = blockIdx.y * 64, n0 = blockIdx.x * 64;
    const int tr = threadIdx.x >> 4, tc = (threadIdx.x & 15) * 4;
    #pragma unroll
    for (int i = 0; i < 4; ++i) {
        int r = tr + i * 16;
        float4 w = *reinterpret_cast<const float4*>(W + (size_t)(k0 + r) * N + n0 + tc);
        s[r][tc + 0] = f2bf(w.x); s[r][tc + 1] = f2bf(w.y);
        s[r][tc + 2] = f2bf(w.z); s[r][tc + 3] = f2bf(w.w);
    }
    __syncthreads();
    #pragma unroll
    for (int i = 0; i < 4; ++i) {
        int n = tr + i * 16;
        u16 tmp[4];
        #pragma unroll
        for (int e = 0; e < 4; ++e) tmp[e] = s[tc + e][n];
        *reinterpret_cast<uint2*>(Wt + (size_t)(n0 + n) * K + k0 + tc) =
            *reinterpret_cast<const uint2*>(tmp);
    }
}

// ---------- 3-in-1 1024x1024 convert+transpose (q,k,v weights, one launch) ----------
__global__ __launch_bounds__(256)
void convT3_k(const float* __restrict__ W0, const float* __restrict__ W1p,
              const float* __restrict__ W2p, u16* __restrict__ Wt)
{
    __shared__ u16 s[64][72];
    const float* W = blockIdx.z == 0 ? W0 : blockIdx.z == 1 ? W1p : W2p;
    u16* dst = Wt + (size_t)blockIdx.z * CDIM * CDIM;
    const int k0 = blockIdx.y * 64, n0 = blockIdx.x * 64;
    const int tr = threadIdx.x >> 4, tc = (threadIdx.x & 15) * 4;
    #pragma unroll
    for (int i = 0; i < 4; ++i) {
        int r = tr + i * 16;
        float4 w = *reinterpret_cast<const float4*>(W + (size_t)(k0 + r) * CDIM + n0 + tc);
        s[r][tc + 0] = f2bf(w.x); s[r][tc + 1] = f2bf(w.y);
        s[r][tc + 2] = f2bf(w.z); s[r][tc + 3] = f2bf(w.w);
    }
    __syncthreads();
    #pragma unroll
    for (int i = 0; i < 4; ++i) {
        int n = tr + i * 16;
        u16 tmp[4];
        #pragma unroll
        for (int e = 0; e < 4; ++e) tmp[e] = s[tc + e][n];
        *reinterpret_cast<uint2*>(dst + (size_t)(n0 + n) * CDIM + k0 + tc) =
            *reinterpret_cast<const uint2*>(tmp);
    }
}

// ---------- head weight: fp32 [16][101][1024] -> split-bf16 W' [16][128][3072]
__global__ __launch_bounds__(256)
void conv_head_k(const float* __restrict__ HW, u16* __restrict__ Wt)
{
    const int o = blockIdx.x, e = blockIdx.y;   // grid (128, 16)
    const int c = threadIdx.x * 4;
    u16 hi[4] = {0, 0, 0, 0}, lo[4] = {0, 0, 0, 0};
    if (o < 101) {
        float4 w = *reinterpret_cast<const float4*>(HW + ((size_t)e * 101 + o) * 1024 + c);
        hi[0] = f2bf(w.x); hi[1] = f2bf(w.y); hi[2] = f2bf(w.z); hi[3] = f2bf(w.w);
        lo[0] = f2bf(w.x - bf2f(hi[0])); lo[1] = f2bf(w.y - bf2f(hi[1]));
        lo[2] = f2bf(w.z - bf2f(hi[2])); lo[3] = f2bf(w.w - bf2f(hi[3]));
    }
    u16* wr = Wt + (size_t)(e * 128 + o) * 3072;
    *reinterpret_cast<uint2*>(wr + c)        = *reinterpret_cast<const uint2*>(hi);
    *reinterpret_cast<uint2*>(wr + 1024 + c) = *reinterpret_cast<const uint2*>(hi);
    *reinterpret_cast<uint2*>(wr + 2048 + c) = *reinterpret_cast<const uint2*>(lo);
}

// ---------- bias pack: bbuf = concat(bq, bk, bv) for one layer ----------
__global__ __launch_bounds__(256)
void pack_bias_k(const float* __restrict__ a, const float* __restrict__ b,
                 const float* __restrict__ c, float* __restrict__ o)
{
    const int i = threadIdx.x * 4;
    const float* s = blockIdx.x == 0 ? a : blockIdx.x == 1 ? b : c;
    *reinterpret_cast<float4*>(o + (size_t)blockIdx.x * 1024 + i) =
        *reinterpret_cast<const float4*>(s + i);
}

// ---------- GEMM: C[M][N] = A_bf16[M][K] @ Bt_bf16[N][K]^T ----------
// R8: counted-vmcnt two-barrier K-loop (T4): barrier_A protects the buffer
// being overwritten (lgkmcnt only, no vmem drain); stage(t+1) issues BEFORE
// the wait for tile t; vmcnt(8) leaves tile t+1's 8 loads in flight across
// barrier_B (never drains to 0 mid-loop). Bias pre-loaded + vmcnt(0)-fenced
// before first stage so exactly 8 loads/wave/tile are in the vmcnt queue.
// 128x128 tile, 4 waves 2x2, acc[4][4], BK=64 two k-half planes, dbuf 64KB.
// EPI 0: out bf16 (+V-transpose if vtout)  EPI 1: gelu->bf16
// EPI 2: streaming fp32 partial to resid[bz]
// EPI 3: head -- by in [0,16): weight base by*128*K, grouped A rows by*128..
template<int EPI>
__global__ __launch_bounds__(256, 2)
void gemm_bt(const u16* __restrict__ A, const u16* __restrict__ Bt,
             const float* __restrict__ bias, u16* __restrict__ outb,
             float* __restrict__ resid, u16* __restrict__ vtout,
             const int N, const int K, const int KCH)
{
    __shared__ __align__(16) u16 sA[2][2][128 * 32];   // [buf][khalf][row*32+k]
    __shared__ __align__(16) u16 sB[2][2][128 * 32];
    const int tid = threadIdx.x;
    const int lane = tid & 63, wv = tid >> 6;
    int bx, by, bz;
    tile_map(bx, by, bz);
    const int m0 = by * 128, n0 = bx * 128;
    const int kbeg = bz * KCH, kend = bz * KCH + KCH;
    const int fr = lane & 15, fq = lane >> 4;
    const int wm = wv & 1, wn = wv >> 1;
    const int srow = lane >> 2, schunk = (lane & 3) * 8;  // staging: 4 lanes/row
    const u16* Bt2 = (EPI == 3) ? Bt + (size_t)by * 128 * K : Bt;
    f32x4 acc[4][4] = {};

    // pre-load bias so the in-loop vmcnt counts are exact (8 loads per stage)
    float bias_r[4];
    #pragma unroll
    for (int nj = 0; nj < 4; ++nj) {
        const int col = n0 + wn * 64 + nj * 16 + fr;
        bias_r[nj] = (EPI == 3) ? 0.0f
                     : (EPI == 2 && bz != 0) ? 0.0f : bias[col];
    }

    auto stage = [&](int k0, int buf) {
        #pragma unroll
        for (int kk = 0; kk < 2; ++kk)
            #pragma unroll
            for (int i = 0; i < 2; ++i) {
                const int reg = i * 4 + wv;             // 16-row region, 8 regions
                gload_lds16(A  + (size_t)(m0 + reg * 16 + srow) * K + k0 + kk * 32 + schunk,
                            &sA[buf][kk][reg * 512]);
                gload_lds16(Bt2 + (size_t)(n0 + reg * 16 + srow) * K + k0 + kk * 32 + schunk,
                            &sB[buf][kk][reg * 512]);
            }
    };

    asm volatile("s_waitcnt vmcnt(0)" ::: "memory");   // bias loads retired
    stage(kbeg, 0);                                    // 8 loads in flight
    int cur = 0;
    for (int k0 = kbeg; k0 < kend; k0 += 64) {
        // barrier A: all waves done READING buf[cur^1] (prev compute);
        // safe to overwrite it. No vmem drain here.
        asm volatile("s_waitcnt lgkmcnt(0)" ::: "memory");
        __builtin_amdgcn_s_barrier();
        if (k0 + 64 < kend) {
            stage(k0 + 64, cur ^ 1);                   // +8 loads (16 in flight)
            asm volatile("s_waitcnt vmcnt(8)" ::: "memory");   // tile-k0's 8 landed
        } else {
            asm volatile("s_waitcnt vmcnt(0)" ::: "memory");
        }
        __builtin_amdgcn_s_barrier();                  // tile k0 resident for all
        __builtin_amdgcn_s_setprio(1);
        #pragma unroll
        for (int kk = 0; kk < 2; ++kk) {
            short8 af[4], bf[4];
            #pragma unroll
            for (int mi = 0; mi < 4; ++mi)
                af[mi] = *reinterpret_cast<const short8*>(
                    &sA[cur][kk][(wm * 64 + mi * 16 + fr) * 32 + fq * 8]);
            #pragma unroll
            for (int nj = 0; nj < 4; ++nj)
                bf[nj] = *reinterpret_cast<const short8*>(
                    &sB[cur][kk][(wn * 64 + nj * 16 + fr) * 32 + fq * 8]);
            #pragma unroll
            for (int mi = 0; mi < 4; ++mi)
                #pragma unroll
                for (int nj = 0; nj < 4; ++nj)
                    acc[mi][nj] = __builtin_amdgcn_mfma_f32_16x16x32_bf16(af[mi], bf[nj], acc[mi][nj], 0, 0, 0);
        }
        __builtin_amdgcn_s_setprio(0);
        cur ^= 1;
    }

    #pragma unroll
    for (int nj = 0; nj < 4; ++nj) {
        const int col = n0 + wn * 64 + nj * 16 + fr;
        const float bias_v = bias_r[nj];
        #pragma unroll
        for (int mi = 0; mi < 4; ++mi) {
            const int rowb = m0 + wm * 64 + mi * 16 + fq * 4;
            if (EPI == 0 && vtout != nullptr && col >= 2048) {
                // V part of qkv -> transposed [b*16+h][d][t] bf16, packed 4 t's
                const int bidx = rowb >> 10, t = rowb & 1023, hd = col - 2048;
                u16 t4[4];
                #pragma unroll
                for (int r = 0; r < 4; ++r) t4[r] = f2bf(acc[mi][nj][r] + bias_v);
                *reinterpret_cast<uint2*>(
                    vtout + ((size_t)(bidx * 16 + (hd >> 6)) * 64 + (hd & 63)) * 1024 + t) =
                    *reinterpret_cast<const uint2*>(t4);
            } else {
                #pragma unroll
                for (int r = 0; r < 4; ++r) {
                    const int row = rowb + r;
                    float cv = acc[mi][nj][r] + bias_v;
                    if (EPI == 0) {
                        outb[(size_t)row * N + col] = f2bf(cv);
                    } else if (EPI == 1) {
                        float gl = 0.5f * cv * (1.0f + erff(cv * 0.70710678118654752f));
                        outb[(size_t)row * N + col] = f2bf(gl);
                    } else if (EPI == 2) {
                        resid[((size_t)bz * NROWS + row) * N + col] = cv;  // streaming partial
                    } else {
                        resid[((size_t)bz * NROWS + row) * 128 + col] = cv;
                    }
                }
            }
        }
    }
}

// ---------- head reduce: out[b*1024 + slot*16 + e][col] = sum_z P[z][pr][col] ----------
__global__ __launch_bounds__(128)
void head_red_k(const float* __restrict__ P, float* __restrict__ out)
{
    const int pr = blockIdx.x;             // e*128 + b*64 + slot
    const int col = threadIdx.x;           // [0,128)
    const int e = pr >> 7, rem = pr & 127, b = rem >> 6, slot = rem & 63;
    float s = 0.0f;
    #pragma unroll
    for (int z = 0; z < 8; ++z)
        s += P[((size_t)z * NROWS + pr) * 128 + col];
    if (col < 101)
        out[((size_t)(b << 10) + (slot << 4) + e) * 101 + col] = s;
}

// ---------- flash attention v2: swapped QK^T, in-register P, split-s ----------
__global__ __launch_bounds__(256, 4)
void attn_k(const u16* __restrict__ QKV, const u16* __restrict__ VT,
            float* __restrict__ po, float* __restrict__ plsum)
{
    __shared__ __align__(16) u16 sK[2][64][72];
    __shared__ __align__(16) u16 sV[2][64][72];   // [d][s]
    const int tid = threadIdx.x, lane = tid & 63, wv = tid >> 6;
    const int fr = lane & 15, fq = lane >> 4;
    int bx, by, bz;
    tile_map(bx, by, bz);
    const int qt = bx, h = by, b = bz >> 1, sc = bz & 1;
    const int q0 = qt * 64;
    const int nt = qt + 1, h1 = (nt + 1) >> 1;          // ceil(nt/2)
    const int stbeg = sc ? h1 : 0, stend = sc ? nt : h1;
    const u16* Qb = QKV + (size_t)b * TDIM * 3072 + h * HD;
    const u16* Vb = VT + ((size_t)(b * HEADS + h) * HD) * TDIM;
    const int r0 = tid >> 3, c0 = (tid & 7) * 8;        // staging: 8 chunks/row

    const u16* qp = Qb + (size_t)(q0 + wv * 16 + fr) * 3072 + fq * 8;
    short8 aQ0 = *reinterpret_cast<const short8*>(qp);
    short8 aQ1 = *reinterpret_cast<const short8*>(qp + 32);

    f32x4 o[4] = {};
    float lsum = 0.0f;
    int cur = 0;

    if (stbeg < stend) {
        #pragma unroll
        for (int i = 0; i < 2; ++i) {
            const int r = r0 + i * 32;
            *reinterpret_cast<uint4*>(&sK[0][r][c0]) =
                *reinterpret_cast<const uint4*>(Qb + 1024 + (size_t)(stbeg * 64 + r) * 3072 + c0);
            *reinterpret_cast<uint4*>(&sV[0][r][c0]) =
                *reinterpret_cast<const uint4*>(Vb + (size_t)r * TDIM + stbeg * 64 + c0);
        }
        __syncthreads();
    }

    for (int st = stbeg; st < stend; ++st) {
        const int s0 = st * 64;
        const bool pf = (st + 1) < stend;
        uint4 pk[2], pv[2];
        if (pf) {
            #pragma unroll
            for (int i = 0; i < 2; ++i) {
                const int r = r0 + i * 32;
                pk[i] = *reinterpret_cast<const uint4*>(Qb + 1024 + (size_t)(s0 + 64 + r) * 3072 + c0);
                pv[i] = *reinterpret_cast<const uint4*>(Vb + (size_t)r * TDIM + s0 + 64 + c0);
            }
        }
        // S^T strips: sacc[j][r] = S[q=q0+wv*16+fr][s = s0 + j*16 + fq*4 + r]
        f32x4 sacc[4] = {};
        #pragma unroll
        for (int j = 0; j < 4; ++j) {
            short8 k0f = *reinterpret_cast<const short8*>(&sK[cur][j * 16 + fr][fq * 8]);
            sacc[j] = __builtin_amdgcn_mfma_f32_16x16x32_bf16(k0f, aQ0, sacc[j], 0, 0, 0);
            short8 k1f = *reinterpret_cast<const short8*>(&sK[cur][j * 16 + fr][32 + fq * 8]);
            sacc[j] = __builtin_amdgcn_mfma_f32_16x16x32_bf16(k1f, aQ1, sacc[j], 0, 0, 0);
        }
        const int qrow = q0 + wv * 16 + fr;
        u16 pb[4][4];
        #pragma unroll
        for (int j = 0; j < 4; ++j)
            #pragma unroll
            for (int r = 0; r < 4; ++r) {
                const int scol = s0 + j * 16 + fq * 4 + r;
                const bool keep = (scol <= qrow) && ((scol & 15) != 15);
                const float p = keep ? __expf(sacc[j][r] * 0.125f) : 0.0f;
                const u16 hb = f2bf(p);
                pb[j][r] = hb;
                lsum += bf2f(hb);
            }
        union { unsigned u[4]; short8 v; } a0, a1;
        a0.u[0] = (unsigned)pb[0][0] | ((unsigned)pb[0][1] << 16);
        a0.u[1] = (unsigned)pb[0][2] | ((unsigned)pb[0][3] << 16);
        a0.u[2] = (unsigned)pb[1][0] | ((unsigned)pb[1][1] << 16);
        a0.u[3] = (unsigned)pb[1][2] | ((unsigned)pb[1][3] << 16);
        a1.u[0] = (unsigned)pb[2][0] | ((unsigned)pb[2][1] << 16);
        a1.u[1] = (unsigned)pb[2][2] | ((unsigned)pb[2][3] << 16);
        a1.u[2] = (unsigned)pb[3][0] | ((unsigned)pb[3][1] << 16);
        a1.u[3] = (unsigned)pb[3][2] | ((unsigned)pb[3][3] << 16);
        #pragma unroll
        for (int j = 0; j < 4; ++j) {
            const u16* vrow = &sV[cur][j * 16 + fr][0];
            short4v v0 = *reinterpret_cast<const short4v*>(vrow + fq * 4);
            short4v v1 = *reinterpret_cast<const short4v*>(vrow + 16 + fq * 4);
            short8 bV0 = __builtin_shufflevector(v0, v1, 0, 1, 2, 3, 4, 5, 6, 7);
            o[j] = __builtin_amdgcn_mfma_f32_16x16x32_bf16(a0.v, bV0, o[j], 0, 0, 0);
            short4v v2 = *reinterpret_cast<const short4v*>(vrow + 32 + fq * 4);
            short4v v3 = *reinterpret_cast<const short4v*>(vrow + 48 + fq * 4);
            short8 bV1 = __builtin_shufflevector(v2, v3, 0, 1, 2, 3, 4, 5, 6, 7);
            o[j] = __builtin_amdgcn_mfma_f32_16x16x32_bf16(a1.v, bV1, o[j], 0, 0, 0);
        }
        if (pf) {
            #pragma unroll
            for (int i = 0; i < 2; ++i) {
                const int r = r0 + i * 32;
                *reinterpret_cast<uint4*>(&sK[cur ^ 1][r][c0]) = pk[i];
                *reinterpret_cast<uint4*>(&sV[cur ^ 1][r][c0]) = pv[i];
            }
            __syncthreads();
            cur ^= 1;
        }
    }

    lsum += __shfl_xor(lsum, 16);
    lsum += __shfl_xor(lsum, 32);

    const int tl = (bz * 16 + h) * 16 + qt;
    float* pt = po + (size_t)tl * 4096;
    #pragma unroll
    for (int j = 0; j < 4; ++j)
        #pragma unroll
        for (int r = 0; r < 4; ++r)
            pt[(wv * 16 + fq * 4 + r) * 64 + j * 16 + fr] = o[j][r];
    if (fq == 0) plsum[(size_t)tl * 64 + wv * 16 + fr] = lsum;
}

// ---------- combine split-s attention partials: y = (o0+o1)/(l0+l1) ----------
__global__ __launch_bounds__(256)
void attn_comb_k(const float* __restrict__ po, const float* __restrict__ plsum,
                 u16* __restrict__ Y)
{
    const int qt = blockIdx.x, h = blockIdx.y, b = blockIdx.z;
    const int t0 = ((b * 2 + 0) * 16 + h) * 16 + qt;
    const int t1 = ((b * 2 + 1) * 16 + h) * 16 + qt;
    const float* p0 = po + (size_t)t0 * 4096;
    const float* p1 = po + (size_t)t1 * 4096;
    const float* l0 = plsum + (size_t)t0 * 64;
    const float* l1 = plsum + (size_t)t1 * 64;
    #pragma unroll
    for (int i = 0; i < 4; ++i) {
        const int f4 = threadIdx.x + i * 256;           // float4 index in [0,1024)
        const int q = f4 >> 4, d4 = (f4 & 15) * 4;
        float4 a = *reinterpret_cast<const float4*>(p0 + f4 * 4);
        float4 c = *reinterpret_cast<const float4*>(p1 + f4 * 4);
        const float rl = 1.0f / (l0[q] + l1[q]);
        u16 t4[4] = { f2bf((a.x + c.x) * rl), f2bf((a.y + c.y) * rl),
                      f2bf((a.z + c.z) * rl), f2bf((a.w + c.w) * rl) };
        *reinterpret_cast<uint2*>(
            Y + ((size_t)(b * TDIM + qt * 64 + q)) * CDIM + h * HD + d4) =
            *reinterpret_cast<const uint2*>(t4);
    }
}

// ---------- launch ----------
extern "C" void kernel_launch(void* const* d_in, const int* in_sizes, int n_in,
                              void* d_out, int out_size, void* d_ws, size_t ws_size,
                              hipStream_t stream)
{
    const int*   tokens = (const int*)  d_in[0];
    const float* tok_emb= (const float*)d_in[1];
    const float* pos_emb= (const float*)d_in[2];
    const float* Wq = (const float*)d_in[3];
    const float* bq = (const float*)d_in[4];
    const float* Wk = (const float*)d_in[5];
    const float* bk = (const float*)d_in[6];
    const float* Wv = (const float*)d_in[7];
    const float* bv = (const float*)d_in[8];
    const float* Wp = (const float*)d_in[9];
    const float* bp = (const float*)d_in[10];
    const float* ln1w = (const float*)d_in[11];
    const float* ln1b = (const float*)d_in[12];
    const float* ln2w = (const float*)d_in[13];
    const float* ln2b = (const float*)d_in[14];
    const float* W1 = (const float*)d_in[15];
    const float* b1 = (const float*)d_in[16];
    const float* W2 = (const float*)d_in[17];
    const float* b2 = (const float*)d_in[18];
    const float* lnfw = (const float*)d_in[19];
    const float* lnfb = (const float*)d_in[20];
    const float* head_w = (const float*)d_in[21];
    float* out = (float*)d_out;

    // workspace (100 MB + 12 KB):
    //  0..8M    x fp32 residual          } head phase: hpart fp32 [8][2048][128]
    //  8..12M   hbuf bf16 == yb bf16 (disjoint in time)
    // 12..24M   qkv bf16 / mid bf16 (12..28M)  } head phase: xg A' bf16 [2048][3072]
    // 24..28M   vT bf16
    // 28..36M   wbuf bf16 (converted weights)
    // 36..100M  pbuf fp32 split-K partials (4 x 8MB used) / attn po+plsum /
    //           head-phase whp W' bf16 [16][128][3072] at 36..48M
    // 100M..    bbuf fp32 [3072]
    char* ws = (char*)d_ws;
    float* x    = (float*)(ws);
    float* hpart= (float*)(ws);
    u16*   hbuf = (u16*)  (ws + (8u  << 20));
    u16*   yb   = (u16*)  (ws + (8u  << 20));
    u16*   qkv  = (u16*)  (ws + (12u << 20));
    u16*   xg   = (u16*)  (ws + (12u << 20));
    u16*   vt   = (u16*)  (ws + (24u << 20));
    u16*   mid  = (u16*)  (ws + (12u << 20));
    u16*   wbuf = (u16*)  (ws + (28u << 20));
    float* pbuf = (float*)(ws + (36u << 20));
    u16*   whp  = (u16*)  (ws + (36u << 20));
    float* po   = (float*)(ws + (36u << 20));
    float* plsum= (float*)(ws + (53u << 20));
    float* bbuf = (float*)(ws + (100u << 20));

    embed_k<<<NROWS, 256, 0, stream>>>(tokens, tok_emb, pos_emb, x);

    for (int l = 0; l < 4; ++l) {
        const size_t wo = (size_t)l * CDIM * CDIM;
        convT3_k<<<dim3(16, 16, 3), 256, 0, stream>>>(Wq + wo, Wk + wo, Wv + wo, wbuf);
        pack_bias_k<<<3, 256, 0, stream>>>(bq + l * CDIM, bk + l * CDIM, bv + l * CDIM, bbuf);

        if (l == 0)
            ln_k<true><<<NROWS, 256, 0, stream>>>(x, ln1w, ln1b, hbuf);
        else
            ln_red_k<0, 4><<<NROWS, 256, 0, stream>>>(x, pbuf, ln1w + l * CDIM, ln1b + l * CDIM, hbuf);
        gemm_bt<0><<<dim3(24, 16, 1), 256, 0, stream>>>(hbuf, wbuf, bbuf, qkv, nullptr, vt, 3072, CDIM, CDIM);
        attn_k<<<dim3(16, HEADS, 4), 256, 0, stream>>>(qkv, vt, po, plsum);
        attn_comb_k<<<dim3(16, HEADS, 2), 256, 0, stream>>>(po, plsum, yb);

        convT_k<<<dim3(16, 16), 256, 0, stream>>>(Wp + wo, wbuf, CDIM, CDIM);
        gemm_bt<2><<<dim3(8, 16, 2), 256, 0, stream>>>(yb, wbuf, bp + l * CDIM, nullptr, pbuf, nullptr, CDIM, CDIM, 512);

        ln_red_k<0, 2><<<NROWS, 256, 0, stream>>>(x, pbuf, ln2w + l * CDIM, ln2b + l * CDIM, hbuf);
        convT_k<<<dim3(64, 16), 256, 0, stream>>>(W1 + (size_t)l * CDIM * F4, wbuf, CDIM, F4);
        gemm_bt<1><<<dim3(32, 16, 1), 256, 0, stream>>>(hbuf, wbuf, b1 + l * F4, mid, nullptr, nullptr, F4, CDIM, CDIM);
        convT_k<<<dim3(16, 64), 256, 0, stream>>>(W2 + (size_t)l * F4 * CDIM, wbuf, F4, CDIM);
        gemm_bt<2><<<dim3(8, 16, 4), 256, 0, stream>>>(mid, wbuf, b2 + l * CDIM, nullptr, pbuf, nullptr, CDIM, F4, CDIM);
    }

    // head: final LN -> split-bf16 A' (xg), W' (whp), one K=3072 MFMA gemm, reduce
    ln_red_k<2, 4><<<NROWS, 256, 0, stream>>>(x, pbuf, lnfw, lnfb, xg);
    conv_head_k<<<dim3(128, 16), 256, 0, stream>>>(head_w, whp);
    gemm_bt<3><<<dim3(1, 16, 8), 256, 0, stream>>>(xg, whp, nullptr, nullptr, hpart, nullptr, 128, 3072, 384);
    head_red_k<<<NROWS, 128, 0, stream>>>(hpart, out);
}

// Round 9
// 918.553 us; speedup vs baseline: 1.0843x; 1.0151x over previous
//
#include <hip/hip_runtime.h>
#include <hip/hip_bf16.h>
#include <math.h>

// ---------- common types ----------
typedef unsigned short u16;
typedef __attribute__((ext_vector_type(8))) short short8;   // 8 bf16 = 4 VGPRs (MFMA A/B frag)
typedef __attribute__((ext_vector_type(4))) short short4v;  // 4 bf16
typedef __attribute__((ext_vector_type(4))) float f32x4;    // MFMA C/D frag

#define CDIM 1024
#define TDIM 1024
#define NROWS 2048   // B*T
#define HEADS 16
#define HD 64
#define F4 4096

// round-to-nearest-even fp32 -> bf16 bits
__device__ __forceinline__ u16 f2bf(float f) {
    union { float f; unsigned u; } v; v.f = f;
    unsigned r = v.u + 0x7fffu + ((v.u >> 16) & 1u);
    return (u16)(r >> 16);
}
__device__ __forceinline__ float bf2f(u16 h) {
    union { unsigned u; float f; } v; v.u = (unsigned)h << 16; return v.f;
}

// async global->LDS, 16 bytes per lane; lds base must be wave-uniform
__device__ __forceinline__ void gload_lds16(const void* g, void* lds) {
    __builtin_amdgcn_global_load_lds(
        (const __attribute__((address_space(1))) unsigned int*)g,
        (__attribute__((address_space(3))) unsigned int*)lds,
        16, 0, 0);
}

// ---------- XCD-bijective + 2D-grouped tile swizzle ----------
// R0 result: FETCH_SIZE 69.7->16.4MB on FFN2 (keep).
__device__ __forceinline__ void tile_map(int& bx, int& by, int& bz)
{
    const int gx = gridDim.x, gy = gridDim.y;
    const int fid = blockIdx.x + gx * (blockIdx.y + gy * blockIdx.z);
    const int nwg = gx * gy * gridDim.z;
    const int q = nwg >> 3, r = nwg & 7;
    const int xcd = fid & 7, t = fid >> 3;
    const int n = ((xcd < r) ? xcd * (q + 1) : r * (q + 1) + (xcd - r) * q) + t;
    const int nxy = gx * gy;
    bz = n / nxy;
    const int xy = n - bz * nxy;
    const int per_group = gx << 3;
    const int grp = xy / per_group;
    const int in = xy - grp * per_group;
    const int y0 = grp << 3;
    const int rem = gy - y0;
    const int gh = rem < 8 ? rem : 8;
    by = y0 + (in % gh);
    bx = in / gh;
}

// ---------- embedding: x = tok_emb[tok] + pos_emb ----------
__global__ __launch_bounds__(256)
void embed_k(const int* __restrict__ tok, const float* __restrict__ te,
             const float* __restrict__ pe, float* __restrict__ X)
{
    const int row = blockIdx.x;          // b*1024 + t
    const int t = row & (TDIM - 1);
    const int tk = tok[row];
    const int c = threadIdx.x * 4;
    float4 a = *reinterpret_cast<const float4*>(te + (size_t)tk * CDIM + c);
    float4 b = *reinterpret_cast<const float4*>(pe + (size_t)t * CDIM + c);
    a.x += b.x; a.y += b.y; a.z += b.z; a.w += b.w;
    *reinterpret_cast<float4*>(X + (size_t)row * CDIM + c) = a;
}

// ---------- layernorm over C=1024, fp32 stats; out bf16 ----------
template<bool BF16OUT>
__global__ __launch_bounds__(256)
void ln_k(const float* __restrict__ X, const float* __restrict__ g,
          const float* __restrict__ be, void* __restrict__ outp)
{
    __shared__ float red[4], red2[4];
    const int row = blockIdx.x, tid = threadIdx.x;
    const float* xr = X + (size_t)row * CDIM;
    const int c = tid * 4;
    float4 xv = *reinterpret_cast<const float4*>(xr + c);
    float s  = xv.x + xv.y + xv.z + xv.w;
    float s2 = xv.x*xv.x + xv.y*xv.y + xv.z*xv.z + xv.w*xv.w;
    #pragma unroll
    for (int off = 32; off; off >>= 1) {
        s  += __shfl_xor(s, off);
        s2 += __shfl_xor(s2, off);
    }
    if ((tid & 63) == 0) { red[tid >> 6] = s; red2[tid >> 6] = s2; }
    __syncthreads();
    const float ts  = red[0] + red[1] + red[2] + red[3];
    const float ts2 = red2[0] + red2[1] + red2[2] + red2[3];
    const float mu  = ts * (1.0f / CDIM);
    const float var = ts2 * (1.0f / CDIM) - mu * mu;
    const float rs  = rsqrtf(var + 1e-5f);
    float4 gv = *reinterpret_cast<const float4*>(g + c);
    float4 bv = *reinterpret_cast<const float4*>(be + c);
    float o0 = (xv.x - mu) * rs * gv.x + bv.x;
    float o1 = (xv.y - mu) * rs * gv.y + bv.y;
    float o2 = (xv.z - mu) * rs * gv.z + bv.z;
    float o3 = (xv.w - mu) * rs * gv.w + bv.w;
    if (BF16OUT) {
        u16 tmp[4] = { f2bf(o0), f2bf(o1), f2bf(o2), f2bf(o3) };
        u16* o = (u16*)outp + (size_t)row * CDIM + c;
        *reinterpret_cast<uint2*>(o) = *reinterpret_cast<const uint2*>(tmp);
    } else {
        float4 ov = { o0, o1, o2, o3 };
        *reinterpret_cast<float4*>((float*)outp + (size_t)row * CDIM + c) = ov;
    }
}

// ---------- fused split-K reduce + residual update + layernorm ----------
// MODE 0: bf16 out [row][C].  MODE 2: head layout -- split-bf16 A' rows
// [e*128 + b*64 + t/16][3072] = [x_hi | x_lo | x_hi]; skips X write-back.
template<int MODE, int NZ>
__global__ __launch_bounds__(256)
void ln_red_k(float* __restrict__ X, const float* __restrict__ P,
              const float* __restrict__ g, const float* __restrict__ be,
              void* __restrict__ outp)
{
    __shared__ float red[4], red2[4];
    const int row = blockIdx.x, tid = threadIdx.x;
    const int c = tid * 4;
    float4 xv = *reinterpret_cast<const float4*>(X + (size_t)row * CDIM + c);
    #pragma unroll
    for (int z = 0; z < NZ; ++z) {
        float4 pv = *reinterpret_cast<const float4*>(P + ((size_t)z * NROWS + row) * CDIM + c);
        xv.x += pv.x; xv.y += pv.y; xv.z += pv.z; xv.w += pv.w;
    }
    if (MODE != 2)
        *reinterpret_cast<float4*>(X + (size_t)row * CDIM + c) = xv;
    float s  = xv.x + xv.y + xv.z + xv.w;
    float s2 = xv.x*xv.x + xv.y*xv.y + xv.z*xv.z + xv.w*xv.w;
    #pragma unroll
    for (int off = 32; off; off >>= 1) {
        s  += __shfl_xor(s, off);
        s2 += __shfl_xor(s2, off);
    }
    if ((tid & 63) == 0) { red[tid >> 6] = s; red2[tid >> 6] = s2; }
    __syncthreads();
    const float ts  = red[0] + red[1] + red[2] + red[3];
    const float ts2 = red2[0] + red2[1] + red2[2] + red2[3];
    const float mu  = ts * (1.0f / CDIM);
    const float var = ts2 * (1.0f / CDIM) - mu * mu;
    const float rs  = rsqrtf(var + 1e-5f);
    float4 gv = *reinterpret_cast<const float4*>(g + c);
    float4 bv = *reinterpret_cast<const float4*>(be + c);
    float o0 = (xv.x - mu) * rs * gv.x + bv.x;
    float o1 = (xv.y - mu) * rs * gv.y + bv.y;
    float o2 = (xv.z - mu) * rs * gv.z + bv.z;
    float o3 = (xv.w - mu) * rs * gv.w + bv.w;
    if (MODE == 0) {
        u16 tmp[4] = { f2bf(o0), f2bf(o1), f2bf(o2), f2bf(o3) };
        u16* o = (u16*)outp + (size_t)row * CDIM + c;
        *reinterpret_cast<uint2*>(o) = *reinterpret_cast<const uint2*>(tmp);
    } else {
        // split-bf16: x = hi + lo to ~2^-16 relative
        u16 hi[4] = { f2bf(o0), f2bf(o1), f2bf(o2), f2bf(o3) };
        u16 lo[4] = { f2bf(o0 - bf2f(hi[0])), f2bf(o1 - bf2f(hi[1])),
                      f2bf(o2 - bf2f(hi[2])), f2bf(o3 - bf2f(hi[3])) };
        const int b = row >> 10, p = row & 1023;
        const int e = p & 15, slot = p >> 4;
        u16* ar = (u16*)outp + (size_t)(e * 128 + b * 64 + slot) * 3072;
        *reinterpret_cast<uint2*>(ar + c)        = *reinterpret_cast<const uint2*>(hi);
        *reinterpret_cast<uint2*>(ar + 1024 + c) = *reinterpret_cast<const uint2*>(lo);
        *reinterpret_cast<uint2*>(ar + 2048 + c) = *reinterpret_cast<const uint2*>(hi);
    }
}

// ---------- weight convert+transpose: W[K][N] fp32 -> Wt[N][K] bf16 ----------
__global__ __launch_bounds__(256)
void convT_k(const float* __restrict__ W, u16* __restrict__ Wt,
             const int K, const int N)
{
    __shared__ u16 s[64][72];
    const int k0 = blockIdx.y * 64, n0 = blockIdx.x * 64;
    const int tr = threadIdx.x >> 4, tc = (threadIdx.x & 15) * 4;
    #pragma unroll
    for (int i = 0; i < 4; ++i) {
        int r = tr + i * 16;
        float4 w = *reinterpret_cast<const float4*>(W + (size_t)(k0 + r) * N + n0 + tc);
        s[r][tc + 0] = f2bf(w.x); s[r][tc + 1] = f2bf(w.y);
        s[r][tc + 2] = f2bf(w.z); s[r][tc + 3] = f2bf(w.w);
    }
    __syncthreads();
    #pragma unroll
    for (int i = 0; i < 4; ++i) {
        int n = tr + i * 16;
        u16 tmp[4];
        #pragma unroll
        for (int e = 0; e < 4; ++e) tmp[e] = s[tc + e][n];
        *reinterpret_cast<uint2*>(Wt + (size_t)(n0 + n) * K + k0 + tc) =
            *reinterpret_cast<const uint2*>(tmp);
    }
}

// ---------- 3-in-1 1024x1024 convert+transpose (q,k,v weights, one launch) ----------
__global__ __launch_bounds__(256)
void convT3_k(const float* __restrict__ W0, const float* __restrict__ W1p,
              const float* __restrict__ W2p, u16* __restrict__ Wt)
{
    __shared__ u16 s[64][72];
    const float* W = blockIdx.z == 0 ? W0 : blockIdx.z == 1 ? W1p : W2p;
    u16* dst = Wt + (size_t)blockIdx.z * CDIM * CDIM;
    const int k0 = blockIdx.y * 64, n0 = blockIdx.x * 64;
    const int tr = threadIdx.x >> 4, tc = (threadIdx.x & 15) * 4;
    #pragma unroll
    for (int i = 0; i < 4; ++i) {
        int r = tr + i * 16;
        float4 w = *reinterpret_cast<const float4*>(W + (size_t)(k0 + r) * CDIM + n0 + tc);
        s[r][tc + 0] = f2bf(w.x); s[r][tc + 1] = f2bf(w.y);
        s[r][tc + 2] = f2bf(w.z); s[r][tc + 3] = f2bf(w.w);
    }
    __syncthreads();
    #pragma unroll
    for (int i = 0; i < 4; ++i) {
        int n = tr + i * 16;
        u16 tmp[4];
        #pragma unroll
        for (int e = 0; e < 4; ++e) tmp[e] = s[tc + e][n];
        *reinterpret_cast<uint2*>(dst + (size_t)(n0 + n) * CDIM + k0 + tc) =
            *reinterpret_cast<const uint2*>(tmp);
    }
}

// ---------- head weight: fp32 [16][101][1024] -> split-bf16 W' [16][128][3072]
__global__ __launch_bounds__(256)
void conv_head_k(const float* __restrict__ HW, u16* __restrict__ Wt)
{
    const int o = blockIdx.x, e = blockIdx.y;   // grid (128, 16)
    const int c = threadIdx.x * 4;
    u16 hi[4] = {0, 0, 0, 0}, lo[4] = {0, 0, 0, 0};
    if (o < 101) {
        float4 w = *reinterpret_cast<const float4*>(HW + ((size_t)e * 101 + o) * 1024 + c);
        hi[0] = f2bf(w.x); hi[1] = f2bf(w.y); hi[2] = f2bf(w.z); hi[3] = f2bf(w.w);
        lo[0] = f2bf(w.x - bf2f(hi[0])); lo[1] = f2bf(w.y - bf2f(hi[1]));
        lo[2] = f2bf(w.z - bf2f(hi[2])); lo[3] = f2bf(w.w - bf2f(hi[3]));
    }
    u16* wr = Wt + (size_t)(e * 128 + o) * 3072;
    *reinterpret_cast<uint2*>(wr + c)        = *reinterpret_cast<const uint2*>(hi);
    *reinterpret_cast<uint2*>(wr + 1024 + c) = *reinterpret_cast<const uint2*>(hi);
    *reinterpret_cast<uint2*>(wr + 2048 + c) = *reinterpret_cast<const uint2*>(lo);
}

// ---------- bias pack: bbuf = concat(bq, bk, bv) for one layer ----------
__global__ __launch_bounds__(256)
void pack_bias_k(const float* __restrict__ a, const float* __restrict__ b,
                 const float* __restrict__ c, float* __restrict__ o)
{
    const int i = threadIdx.x * 4;
    const float* s = blockIdx.x == 0 ? a : blockIdx.x == 1 ? b : c;
    *reinterpret_cast<float4*>(o + (size_t)blockIdx.x * 1024 + i) =
        *reinterpret_cast<const float4*>(s + i);
}

// ---------- GEMM: C[M][N] = A_bf16[M][K] @ Bt_bf16[N][K]^T ----------
// R8: counted-vmcnt two-barrier K-loop (T4). R9: + T2 chunk-XOR LDS swizzle.
// Layout: [row][32 u16] per kk-plane; physical chunk c' = c ^ ((row>>1)&3).
// Store side: gload_lds writes linearly, so the swizzle is applied by
// permuting the GLOBAL source chunk per lane (schunk = (lane&3)^((lane>>3)&3));
// permutation stays within each 64B row-segment -> coalescing unchanged.
// Read side: ds_read chunk = fq ^ ((fr>>1)&3). Slot = 4(row&1)+(fq^((row>>1)&3))
// -> lanes 0..7 cover all 8 granule-slots -> conflict-free ds_read_b128
// (was 4-way phase conflict, 2.1M SQ_LDS_BANK_CONFLICT).
// EPI 0: out bf16 (+V-transpose if vtout)  EPI 1: gelu->bf16
// EPI 2: streaming fp32 partial to resid[bz]
// EPI 3: head -- by in [0,16): weight base by*128*K, grouped A rows by*128..
template<int EPI>
__global__ __launch_bounds__(256, 2)
void gemm_bt(const u16* __restrict__ A, const u16* __restrict__ Bt,
             const float* __restrict__ bias, u16* __restrict__ outb,
             float* __restrict__ resid, u16* __restrict__ vtout,
             const int N, const int K, const int KCH)
{
    __shared__ __align__(16) u16 sA[2][2][128 * 32];   // [buf][khalf][row*32+k]
    __shared__ __align__(16) u16 sB[2][2][128 * 32];
    const int tid = threadIdx.x;
    const int lane = tid & 63, wv = tid >> 6;
    int bx, by, bz;
    tile_map(bx, by, bz);
    const int m0 = by * 128, n0 = bx * 128;
    const int kbeg = bz * KCH, kend = bz * KCH + KCH;
    const int fr = lane & 15, fq = lane >> 4;
    const int wm = wv & 1, wn = wv >> 1;
    const int srow = lane >> 2;
    const int schunk = (((lane & 3) ^ ((lane >> 3) & 3)) * 8);  // pre-swizzled source
    const int csw = (fr >> 1) & 3;                               // read-side XOR
    const u16* Bt2 = (EPI == 3) ? Bt + (size_t)by * 128 * K : Bt;
    f32x4 acc[4][4] = {};

    // pre-load bias so the in-loop vmcnt counts are exact (8 loads per stage)
    float bias_r[4];
    #pragma unroll
    for (int nj = 0; nj < 4; ++nj) {
        const int col = n0 + wn * 64 + nj * 16 + fr;
        bias_r[nj] = (EPI == 3) ? 0.0f
                     : (EPI == 2 && bz != 0) ? 0.0f : bias[col];
    }

    auto stage = [&](int k0, int buf) {
        #pragma unroll
        for (int kk = 0; kk < 2; ++kk)
            #pragma unroll
            for (int i = 0; i < 2; ++i) {
                const int reg = i * 4 + wv;             // 16-row region, 8 regions
                gload_lds16(A  + (size_t)(m0 + reg * 16 + srow) * K + k0 + kk * 32 + schunk,
                            &sA[buf][kk][reg * 512]);
                gload_lds16(Bt2 + (size_t)(n0 + reg * 16 + srow) * K + k0 + kk * 32 + schunk,
                            &sB[buf][kk][reg * 512]);
            }
    };

    asm volatile("s_waitcnt vmcnt(0)" ::: "memory");   // bias loads retired
    stage(kbeg, 0);                                    // 8 loads in flight
    int cur = 0;
    for (int k0 = kbeg; k0 < kend; k0 += 64) {
        // barrier A: all waves done READING buf[cur^1]; safe to overwrite.
        asm volatile("s_waitcnt lgkmcnt(0)" ::: "memory");
        __builtin_amdgcn_s_barrier();
        if (k0 + 64 < kend) {
            stage(k0 + 64, cur ^ 1);                   // +8 loads (16 in flight)
            asm volatile("s_waitcnt vmcnt(8)" ::: "memory");   // tile-k0's 8 landed
        } else {
            asm volatile("s_waitcnt vmcnt(0)" ::: "memory");
        }
        __builtin_amdgcn_s_barrier();                  // tile k0 resident for all
        __builtin_amdgcn_s_setprio(1);
        #pragma unroll
        for (int kk = 0; kk < 2; ++kk) {
            short8 af[4], bf[4];
            #pragma unroll
            for (int mi = 0; mi < 4; ++mi)
                af[mi] = *reinterpret_cast<const short8*>(
                    &sA[cur][kk][(wm * 64 + mi * 16 + fr) * 32 + (fq ^ csw) * 8]);
            #pragma unroll
            for (int nj = 0; nj < 4; ++nj)
                bf[nj] = *reinterpret_cast<const short8*>(
                    &sB[cur][kk][(wn * 64 + nj * 16 + fr) * 32 + (fq ^ csw) * 8]);
            #pragma unroll
            for (int mi = 0; mi < 4; ++mi)
                #pragma unroll
                for (int nj = 0; nj < 4; ++nj)
                    acc[mi][nj] = __builtin_amdgcn_mfma_f32_16x16x32_bf16(af[mi], bf[nj], acc[mi][nj], 0, 0, 0);
        }
        __builtin_amdgcn_s_setprio(0);
        cur ^= 1;
    }

    #pragma unroll
    for (int nj = 0; nj < 4; ++nj) {
        const int col = n0 + wn * 64 + nj * 16 + fr;
        const float bias_v = bias_r[nj];
        #pragma unroll
        for (int mi = 0; mi < 4; ++mi) {
            const int rowb = m0 + wm * 64 + mi * 16 + fq * 4;
            if (EPI == 0 && vtout != nullptr && col >= 2048) {
                // V part of qkv -> transposed [b*16+h][d][t] bf16, packed 4 t's
                const int bidx = rowb >> 10, t = rowb & 1023, hd = col - 2048;
                u16 t4[4];
                #pragma unroll
                for (int r = 0; r < 4; ++r) t4[r] = f2bf(acc[mi][nj][r] + bias_v);
                *reinterpret_cast<uint2*>(
                    vtout + ((size_t)(bidx * 16 + (hd >> 6)) * 64 + (hd & 63)) * 1024 + t) =
                    *reinterpret_cast<const uint2*>(t4);
            } else {
                #pragma unroll
                for (int r = 0; r < 4; ++r) {
                    const int row = rowb + r;
                    float cv = acc[mi][nj][r] + bias_v;
                    if (EPI == 0) {
                        outb[(size_t)row * N + col] = f2bf(cv);
                    } else if (EPI == 1) {
                        float gl = 0.5f * cv * (1.0f + erff(cv * 0.70710678118654752f));
                        outb[(size_t)row * N + col] = f2bf(gl);
                    } else if (EPI == 2) {
                        resid[((size_t)bz * NROWS + row) * N + col] = cv;  // streaming partial
                    } else {
                        resid[((size_t)bz * NROWS + row) * 128 + col] = cv;
                    }
                }
            }
        }
    }
}

// ---------- head reduce: out[b*1024 + slot*16 + e][col] = sum_z P[z][pr][col] ----------
__global__ __launch_bounds__(128)
void head_red_k(const float* __restrict__ P, float* __restrict__ out)
{
    const int pr = blockIdx.x;             // e*128 + b*64 + slot
    const int col = threadIdx.x;           // [0,128)
    const int e = pr >> 7, rem = pr & 127, b = rem >> 6, slot = rem & 63;
    float s = 0.0f;
    #pragma unroll
    for (int z = 0; z < 8; ++z)
        s += P[((size_t)z * NROWS + pr) * 128 + col];
    if (col < 101)
        out[((size_t)(b << 10) + (slot << 4) + e) * 101 + col] = s;
}

// ---------- flash attention v2: swapped QK^T, in-register P, split-s x4 ----------
// R9: split-s 2->4 chunks (grid.z = b*4+sc, 2048 blocks) -- longest serial
// chain 16 -> 4 s-tiles; partials combine additively (no running max).
__global__ __launch_bounds__(256, 4)
void attn_k(const u16* __restrict__ QKV, const u16* __restrict__ VT,
            float* __restrict__ po, float* __restrict__ plsum)
{
    __shared__ __align__(16) u16 sK[2][64][72];
    __shared__ __align__(16) u16 sV[2][64][72];   // [d][s]
    const int tid = threadIdx.x, lane = tid & 63, wv = tid >> 6;
    const int fr = lane & 15, fq = lane >> 4;
    int bx, by, bz;
    tile_map(bx, by, bz);
    const int qt = bx, h = by, b = bz >> 2, sc = bz & 3;
    const int q0 = qt * 64;
    const int nt = qt + 1;
    const int stbeg = (nt * sc) >> 2, stend = (nt * (sc + 1)) >> 2;
    const u16* Qb = QKV + (size_t)b * TDIM * 3072 + h * HD;
    const u16* Vb = VT + ((size_t)(b * HEADS + h) * HD) * TDIM;
    const int r0 = tid >> 3, c0 = (tid & 7) * 8;        // staging: 8 chunks/row

    const u16* qp = Qb + (size_t)(q0 + wv * 16 + fr) * 3072 + fq * 8;
    short8 aQ0 = *reinterpret_cast<const short8*>(qp);
    short8 aQ1 = *reinterpret_cast<const short8*>(qp + 32);

    f32x4 o[4] = {};
    float lsum = 0.0f;
    int cur = 0;

    if (stbeg < stend) {
        #pragma unroll
        for (int i = 0; i < 2; ++i) {
            const int r = r0 + i * 32;
            *reinterpret_cast<uint4*>(&sK[0][r][c0]) =
                *reinterpret_cast<const uint4*>(Qb + 1024 + (size_t)(stbeg * 64 + r) * 3072 + c0);
            *reinterpret_cast<uint4*>(&sV[0][r][c0]) =
                *reinterpret_cast<const uint4*>(Vb + (size_t)r * TDIM + stbeg * 64 + c0);
        }
        __syncthreads();
    }

    for (int st = stbeg; st < stend; ++st) {
        const int s0 = st * 64;
        const bool pf = (st + 1) < stend;
        uint4 pk[2], pv[2];
        if (pf) {
            #pragma unroll
            for (int i = 0; i < 2; ++i) {
                const int r = r0 + i * 32;
                pk[i] = *reinterpret_cast<const uint4*>(Qb + 1024 + (size_t)(s0 + 64 + r) * 3072 + c0);
                pv[i] = *reinterpret_cast<const uint4*>(Vb + (size_t)r * TDIM + s0 + 64 + c0);
            }
        }
        // S^T strips: sacc[j][r] = S[q=q0+wv*16+fr][s = s0 + j*16 + fq*4 + r]
        f32x4 sacc[4] = {};
        #pragma unroll
        for (int j = 0; j < 4; ++j) {
            short8 k0f = *reinterpret_cast<const short8*>(&sK[cur][j * 16 + fr][fq * 8]);
            sacc[j] = __builtin_amdgcn_mfma_f32_16x16x32_bf16(k0f, aQ0, sacc[j], 0, 0, 0);
            short8 k1f = *reinterpret_cast<const short8*>(&sK[cur][j * 16 + fr][32 + fq * 8]);
            sacc[j] = __builtin_amdgcn_mfma_f32_16x16x32_bf16(k1f, aQ1, sacc[j], 0, 0, 0);
        }
        const int qrow = q0 + wv * 16 + fr;
        u16 pb[4][4];
        #pragma unroll
        for (int j = 0; j < 4; ++j)
            #pragma unroll
            for (int r = 0; r < 4; ++r) {
                const int scol = s0 + j * 16 + fq * 4 + r;
                const bool keep = (scol <= qrow) && ((scol & 15) != 15);
                const float p = keep ? __expf(sacc[j][r] * 0.125f) : 0.0f;
                const u16 hb = f2bf(p);
                pb[j][r] = hb;
                lsum += bf2f(hb);
            }
        union { unsigned u[4]; short8 v; } a0, a1;
        a0.u[0] = (unsigned)pb[0][0] | ((unsigned)pb[0][1] << 16);
        a0.u[1] = (unsigned)pb[0][2] | ((unsigned)pb[0][3] << 16);
        a0.u[2] = (unsigned)pb[1][0] | ((unsigned)pb[1][1] << 16);
        a0.u[3] = (unsigned)pb[1][2] | ((unsigned)pb[1][3] << 16);
        a1.u[0] = (unsigned)pb[2][0] | ((unsigned)pb[2][1] << 16);
        a1.u[1] = (unsigned)pb[2][2] | ((unsigned)pb[2][3] << 16);
        a1.u[2] = (unsigned)pb[3][0] | ((unsigned)pb[3][1] << 16);
        a1.u[3] = (unsigned)pb[3][2] | ((unsigned)pb[3][3] << 16);
        #pragma unroll
        for (int j = 0; j < 4; ++j) {
            const u16* vrow = &sV[cur][j * 16 + fr][0];
            short4v v0 = *reinterpret_cast<const short4v*>(vrow + fq * 4);
            short4v v1 = *reinterpret_cast<const short4v*>(vrow + 16 + fq * 4);
            short8 bV0 = __builtin_shufflevector(v0, v1, 0, 1, 2, 3, 4, 5, 6, 7);
            o[j] = __builtin_amdgcn_mfma_f32_16x16x32_bf16(a0.v, bV0, o[j], 0, 0, 0);
            short4v v2 = *reinterpret_cast<const short4v*>(vrow + 32 + fq * 4);
            short4v v3 = *reinterpret_cast<const short4v*>(vrow + 48 + fq * 4);
            short8 bV1 = __builtin_shufflevector(v2, v3, 0, 1, 2, 3, 4, 5, 6, 7);
            o[j] = __builtin_amdgcn_mfma_f32_16x16x32_bf16(a1.v, bV1, o[j], 0, 0, 0);
        }
        if (pf) {
            #pragma unroll
            for (int i = 0; i < 2; ++i) {
                const int r = r0 + i * 32;
                *reinterpret_cast<uint4*>(&sK[cur ^ 1][r][c0]) = pk[i];
                *reinterpret_cast<uint4*>(&sV[cur ^ 1][r][c0]) = pv[i];
            }
            __syncthreads();
            cur ^= 1;
        }
    }

    lsum += __shfl_xor(lsum, 16);
    lsum += __shfl_xor(lsum, 32);

    const int tl = (bz * 16 + h) * 16 + qt;
    float* pt = po + (size_t)tl * 4096;
    #pragma unroll
    for (int j = 0; j < 4; ++j)
        #pragma unroll
        for (int r = 0; r < 4; ++r)
            pt[(wv * 16 + fq * 4 + r) * 64 + j * 16 + fr] = o[j][r];
    if (fq == 0) plsum[(size_t)tl * 64 + wv * 16 + fr] = lsum;
}

// ---------- combine split-s attention partials: y = (sum o_i)/(sum l_i) ----------
__global__ __launch_bounds__(256)
void attn_comb_k(const float* __restrict__ po, const float* __restrict__ plsum,
                 u16* __restrict__ Y)
{
    const int qt = blockIdx.x, h = blockIdx.y, b = blockIdx.z;
    int t[4];
    #pragma unroll
    for (int i = 0; i < 4; ++i) t[i] = ((b * 4 + i) * 16 + h) * 16 + qt;
    #pragma unroll
    for (int i = 0; i < 4; ++i) {
        const int f4 = threadIdx.x + i * 256;           // float4 index in [0,1024)
        const int q = f4 >> 4, d4 = (f4 & 15) * 4;
        float4 a = *reinterpret_cast<const float4*>(po + (size_t)t[0] * 4096 + f4 * 4);
        float ls = plsum[(size_t)t[0] * 64 + q];
        #pragma unroll
        for (int k = 1; k < 4; ++k) {
            float4 c = *reinterpret_cast<const float4*>(po + (size_t)t[k] * 4096 + f4 * 4);
            a.x += c.x; a.y += c.y; a.z += c.z; a.w += c.w;
            ls += plsum[(size_t)t[k] * 64 + q];
        }
        const float rl = 1.0f / ls;
        u16 t4[4] = { f2bf(a.x * rl), f2bf(a.y * rl),
                      f2bf(a.z * rl), f2bf(a.w * rl) };
        *reinterpret_cast<uint2*>(
            Y + ((size_t)(b * TDIM + qt * 64 + q)) * CDIM + h * HD + d4) =
            *reinterpret_cast<const uint2*>(t4);
    }
}

// ---------- launch ----------
extern "C" void kernel_launch(void* const* d_in, const int* in_sizes, int n_in,
                              void* d_out, int out_size, void* d_ws, size_t ws_size,
                              hipStream_t stream)
{
    const int*   tokens = (const int*)  d_in[0];
    const float* tok_emb= (const float*)d_in[1];
    const float* pos_emb= (const float*)d_in[2];
    const float* Wq = (const float*)d_in[3];
    const float* bq = (const float*)d_in[4];
    const float* Wk = (const float*)d_in[5];
    const float* bk = (const float*)d_in[6];
    const float* Wv = (const float*)d_in[7];
    const float* bv = (const float*)d_in[8];
    const float* Wp = (const float*)d_in[9];
    const float* bp = (const float*)d_in[10];
    const float* ln1w = (const float*)d_in[11];
    const float* ln1b = (const float*)d_in[12];
    const float* ln2w = (const float*)d_in[13];
    const float* ln2b = (const float*)d_in[14];
    const float* W1 = (const float*)d_in[15];
    const float* b1 = (const float*)d_in[16];
    const float* W2 = (const float*)d_in[17];
    const float* b2 = (const float*)d_in[18];
    const float* lnfw = (const float*)d_in[19];
    const float* lnfb = (const float*)d_in[20];
    const float* head_w = (const float*)d_in[21];
    float* out = (float*)d_out;

    // workspace (100 MB + 12 KB):
    //  0..8M    x fp32 residual          } head phase: hpart fp32 [8][2048][128]
    //  8..12M   hbuf bf16 == yb bf16 (disjoint in time)
    // 12..24M   qkv bf16 / mid bf16 (12..28M)  } head phase: xg A' bf16 [2048][3072]
    // 24..28M   vT bf16
    // 28..36M   wbuf bf16 (converted weights)
    // 36..100M  pbuf fp32 split-K partials (4 x 8MB used) / attn po (36..68M)
    //           + plsum (68..68.5M) / head-phase whp W' bf16 at 36..48M
    // 100M..    bbuf fp32 [3072]
    char* ws = (char*)d_ws;
    float* x    = (float*)(ws);
    float* hpart= (float*)(ws);
    u16*   hbuf = (u16*)  (ws + (8u  << 20));
    u16*   yb   = (u16*)  (ws + (8u  << 20));
    u16*   qkv  = (u16*)  (ws + (12u << 20));
    u16*   xg   = (u16*)  (ws + (12u << 20));
    u16*   vt   = (u16*)  (ws + (24u << 20));
    u16*   mid  = (u16*)  (ws + (12u << 20));
    u16*   wbuf = (u16*)  (ws + (28u << 20));
    float* pbuf = (float*)(ws + (36u << 20));
    u16*   whp  = (u16*)  (ws + (36u << 20));
    float* po   = (float*)(ws + (36u << 20));
    float* plsum= (float*)(ws + (68u << 20));
    float* bbuf = (float*)(ws + (100u << 20));

    embed_k<<<NROWS, 256, 0, stream>>>(tokens, tok_emb, pos_emb, x);

    for (int l = 0; l < 4; ++l) {
        const size_t wo = (size_t)l * CDIM * CDIM;
        convT3_k<<<dim3(16, 16, 3), 256, 0, stream>>>(Wq + wo, Wk + wo, Wv + wo, wbuf);
        pack_bias_k<<<3, 256, 0, stream>>>(bq + l * CDIM, bk + l * CDIM, bv + l * CDIM, bbuf);

        if (l == 0)
            ln_k<true><<<NROWS, 256, 0, stream>>>(x, ln1w, ln1b, hbuf);
        else
            ln_red_k<0, 4><<<NROWS, 256, 0, stream>>>(x, pbuf, ln1w + l * CDIM, ln1b + l * CDIM, hbuf);
        gemm_bt<0><<<dim3(24, 16, 1), 256, 0, stream>>>(hbuf, wbuf, bbuf, qkv, nullptr, vt, 3072, CDIM, CDIM);
        attn_k<<<dim3(16, HEADS, 8), 256, 0, stream>>>(qkv, vt, po, plsum);
        attn_comb_k<<<dim3(16, HEADS, 2), 256, 0, stream>>>(po, plsum, yb);

        convT_k<<<dim3(16, 16), 256, 0, stream>>>(Wp + wo, wbuf, CDIM, CDIM);
        gemm_bt<2><<<dim3(8, 16, 2), 256, 0, stream>>>(yb, wbuf, bp + l * CDIM, nullptr, pbuf, nullptr, CDIM, CDIM, 512);

        ln_red_k<0, 2><<<NROWS, 256, 0, stream>>>(x, pbuf, ln2w + l * CDIM, ln2b + l * CDIM, hbuf);
        convT_k<<<dim3(64, 16), 256, 0, stream>>>(W1 + (size_t)l * CDIM * F4, wbuf, CDIM, F4);
        gemm_bt<1><<<dim3(32, 16, 1), 256, 0, stream>>>(hbuf, wbuf, b1 + l * F4, mid, nullptr, nullptr, F4, CDIM, CDIM);
        convT_k<<<dim3(16, 64), 256, 0, stream>>>(W2 + (size_t)l * F4 * CDIM, wbuf, F4, CDIM);
        gemm_bt<2><<<dim3(8, 16, 4), 256, 0, stream>>>(mid, wbuf, b2 + l * CDIM, nullptr, pbuf, nullptr, CDIM, F4, CDIM);
    }

    // head: final LN -> split-bf16 A' (xg), W' (whp), one K=3072 MFMA gemm, reduce
    ln_red_k<2, 4><<<NROWS, 256, 0, stream>>>(x, pbuf, lnfw, lnfb, xg);
    conv_head_k<<<dim3(128, 16), 256, 0, stream>>>(head_w, whp);
    gemm_bt<3><<<dim3(1, 16, 8), 256, 0, stream>>>(xg, whp, nullptr, nullptr, hpart, nullptr, 128, 3072, 384);
    head_red_k<<<NROWS, 128, 0, stream>>>(hpart, out);
}